// Round 8
// baseline (14774.306 us; speedup 1.0000x reference)
//
#include <hip/hip_runtime.h>
#include <stdint.h>

#define BB 64
#define TT 512
#define II 512
#define HH 1024
#define OO 512
#define NBLK 256
#define NTHR 512
#define GG 4            // batch groups (16 batches each)
#define SS 64           // unit slices (16 units each)
#define NB 16           // batches per group
#define US 16           // units per slice
#define NKOCT 192       // K octets: (II+HH)/8
#define KOCT_PW 24      // K octets per wave

// ws float-offsets
#define WS_CTRL 0            // barrier counters
#define WS_HBUF 1280         // 2 slots x (64*1024) fp16 = 65536 floats
#define WS_SLAB 66816        // SS*NKOCT*16*4 uint4 = 786432 uint4 = 3145728 floats
#define WS_SLAB_F (SS*NKOCT*64*4)
#define WS_WFC  (WS_SLAB + WS_SLAB_F)   // 3212544 (512*1024 fp16)
#define WS_X16  (WS_WFC + 262144)       // 3474688 (B*T*I fp16 = 8388608 floats)
#define BTO (BB*TT*OO)
#define BH  (BB*HH)

// LDS: acts [16][193] uint4 (49408 B) | part [8][64][17] fp32 (34816 B)
#define L_PART_OFF 12352
#define L_TOTAL_BYTES 84224

typedef _Float16 h2 __attribute__((ext_vector_type(2)));

#if __has_builtin(__builtin_amdgcn_fdot2)
#define FDOT2(a,b,c) __builtin_amdgcn_fdot2((a),(b),(c),false)
#else
static __device__ __forceinline__ float FDOT2(h2 a, h2 b, float c) {
  return fmaf((float)a.x, (float)b.x, fmaf((float)a.y, (float)b.y, c));
}
#endif

static __device__ __forceinline__ h2 bc_h2(uint32_t v) { return __builtin_bit_cast(h2, v); }
static __device__ __forceinline__ uint32_t pk_u32(float a, float b) {
  return __builtin_bit_cast(uint32_t, __builtin_amdgcn_cvt_pkrtz(a, b));
}

__device__ __forceinline__ float sigm(float v) { return 1.0f / (1.0f + __expf(-v)); }
__device__ __forceinline__ float tanh_c(float v) {
  v = fminf(fmaxf(v, -20.0f), 20.0f);
  float e = __expf(-2.0f * v);
  return (1.0f - e) / (1.0f + e);
}

// agent-scope (sc0 sc1): per-access coherence, NO cache-wide ops
__device__ __forceinline__ uint2 cohere_ld8(const void* p) {
  unsigned long long q = __hip_atomic_load((const unsigned long long*)p,
                                           __ATOMIC_RELAXED, __HIP_MEMORY_SCOPE_AGENT);
  return __builtin_bit_cast(uint2, q);
}
__device__ __forceinline__ void cohere_st4(void* p, uint32_t v) {
  __hip_atomic_store((uint32_t*)p, v, __ATOMIC_RELAXED, __HIP_MEMORY_SCOPE_AGENT);
}

// -------- preprocess: gate slab (row-banded), Wfc fp16, x fp16 --------
// slab idx = ((s*192 + koct)*16 + r)*4 + rq : row m=r*4+rq, u=s*16+(m>>2), gate=m&3
__global__ void __launch_bounds__(256) prep(
    const float* __restrict__ Wf, const float* __restrict__ Wi,
    const float* __restrict__ Wc, const float* __restrict__ Wo,
    const float* __restrict__ Wfc, const float* __restrict__ x,
    float* __restrict__ ws)
{
  const int NG = SS * NKOCT * 64;
  const int NW = 512 * 128;
  int idx = blockIdx.x * 256 + threadIdx.x;
  if (idx < NG) {
    int s = idx / (NKOCT * 64);
    int rem = idx % (NKOCT * 64);
    int koct = rem >> 6, rr = rem & 63;
    int m = (rr >> 2) * 4 + (rr & 3);          // r*4 + rq
    int u = s * US + (m >> 2), gate = m & 3;
    const float* W = (gate == 0) ? Wf : (gate == 1) ? Wi : (gate == 2) ? Wc : Wo;
    const float* src = W + (size_t)u * 1536 + koct * 8;
    uint32_t p[4];
    #pragma unroll
    for (int j = 0; j < 4; ++j) {
      h2 t; t.x = (_Float16)src[2*j]; t.y = (_Float16)src[2*j+1];   // RNE
      p[j] = __builtin_bit_cast(uint32_t, t);
    }
    ((uint4*)(ws + WS_SLAB))[idx] = make_uint4(p[0], p[1], p[2], p[3]);
  } else if (idx < NG + NW) {
    int j2 = idx - NG;
    int o = j2 >> 7, uo = j2 & 127;
    const float* src = Wfc + (size_t)o * 1024 + uo * 8;
    uint32_t p[4];
    #pragma unroll
    for (int j = 0; j < 4; ++j) {
      h2 t; t.x = (_Float16)src[2*j]; t.y = (_Float16)src[2*j+1];
      p[j] = __builtin_bit_cast(uint32_t, t);
    }
    ((uint4*)(ws + WS_WFC))[j2] = make_uint4(p[0], p[1], p[2], p[3]);
  } else {
    int j3 = idx - NG - NW;                     // 0 .. 2097151 (x in 8-float units)
    const float4* src = (const float4*)(x + (size_t)j3 * 8);
    float4 v0 = src[0], v1 = src[1];
    ((uint4*)(ws + WS_X16))[j3] = make_uint4(pk_u32(v0.x,v0.y), pk_u32(v0.z,v0.w),
                                             pk_u32(v1.x,v1.y), pk_u32(v1.z,v1.w));
  }
}

__global__ void __launch_bounds__(NTHR, 1)
lstm_kernel(const float* __restrict__ bf, const float* __restrict__ bi,
            const float* __restrict__ bc, const float* __restrict__ bo,
            const float* __restrict__ bfc,
            float* __restrict__ out, float* __restrict__ ws)
{
  extern __shared__ float ldsf[];
  uint4* acts4 = (uint4*)ldsf;                 // [16][193] uint4
  float* part  = ldsf + L_PART_OFF;            // [8][64][17]

  const int tid  = threadIdx.x;
  const int blk  = blockIdx.x;
  const int wave = tid >> 6;
  const int lane = tid & 63;
  const int g = blk >> 6, s = blk & 63;
  const int b0 = g * NB;
  const int u0 = s * US;

  uint32_t* ctrl  = (uint32_t*)ws;
  uint32_t* rootp = ctrl + g * 32;
  uint32_t* subp  = ctrl + 128 + (g * 8 + (s & 7)) * 32;
  ushort* hb16 = (ushort*)(ws + WS_HBUF);
  const ushort* x16 = (const ushort*)(ws + WS_X16);
  const uint4* wslab = (const uint4*)(ws + WS_SLAB);
  const uint4* wfc4  = (const uint4*)(ws + WS_WFC);

  // gate lanes: rq = row-quad, bq = batch
  const int rq = lane >> 4, bq = lane & 15;
  const size_t wbase = (size_t)s * (NKOCT * 64);

  // stage lanes
  const int sbb = tid >> 5, sc5 = tid & 31;

  // state threads (waves 0-3): bb = tid&15, ul = tid>>4
  float cstate = 0.0f, bsf = 0.f, bsi = 0.f, bsc = 0.f, bso = 0.f;
  if (wave < 4) {
    int u = u0 + (tid >> 4);
    bsf = bf[u]; bsi = bi[u]; bsc = bc[u]; bso = bo[u];
  }
  const float ybias = bfc[s * 8 + wave];

  // prologue: stage acts for step 0 (x_0 fp16 + h_{-1}=0)
  {
    const ushort* xs = x16 + ((size_t)(b0 + sbb) * TT + 0) * II + sc5 * 16;
    acts4[sbb * 193 + sc5 * 2]     = *(const uint4*)xs;
    acts4[sbb * 193 + sc5 * 2 + 1] = *(const uint4*)(xs + 8);
    const ushort* hs = hb16 + (size_t)(b0 + sbb) * HH + sc5 * 32;
    uint2 q[8];
    #pragma unroll
    for (int j = 0; j < 8; ++j) q[j] = cohere_ld8(hs + j * 4);
    #pragma unroll
    for (int j = 0; j < 4; ++j)
      acts4[sbb * 193 + 64 + sc5 * 4 + j] =
          make_uint4(q[2*j].x, q[2*j].y, q[2*j+1].x, q[2*j+1].y);
  }
  __syncthreads();

  for (int it = 0; it <= TT; ++it) {
    // ---- gate GEMM: wave w -> koct [w*24,w*24+24); lane=(rq,bq); 16 rows/lane ----
    if (it < TT) {
      float acc[16];
      #pragma unroll
      for (int r = 0; r < 16; ++r) acc[r] = 0.0f;
      const int k0 = wave * KOCT_PW;
      #pragma unroll 2
      for (int i = 0; i < KOCT_PW; ++i) {
        const int koct = k0 + i;
        uint4 av = acts4[bq * 193 + koct];          // 1 LDS op/wave (16 addrs, 2-way)
        const uint4* wp = wslab + wbase + (size_t)koct * 64 + rq;
        #pragma unroll
        for (int r = 0; r < 16; ++r) {
          uint4 wq = wp[r * 4];                     // 64B line across 4 rq-lanes
          float a = acc[r];
          a = FDOT2(bc_h2(av.x), bc_h2(wq.x), a);
          a = FDOT2(bc_h2(av.y), bc_h2(wq.y), a);
          a = FDOT2(bc_h2(av.z), bc_h2(wq.z), a);
          a = FDOT2(bc_h2(av.w), bc_h2(wq.w), a);
          acc[r] = a;
        }
      }
      #pragma unroll
      for (int r = 0; r < 16; ++r)
        part[(wave * 64 + r * 4 + rq) * 17 + bq] = acc[r];
    }

    // ---- y_{it-1}: wave -> o = s*8+wave; lane=(bb2,uc) ----
    if (it > 0) {
      const int bb2 = lane & 15, uc = lane >> 4;
      float yacc = 0.0f;
      const uint4* wrow = wfc4 + (size_t)(s * 8 + wave) * 128 + uc * 32;
      #pragma unroll 4
      for (int i = 0; i < 32; ++i) {
        uint4 hv = acts4[bb2 * 193 + 64 + uc * 32 + i];
        uint4 wv = wrow[i];
        yacc = FDOT2(bc_h2(hv.x), bc_h2(wv.x), yacc);
        yacc = FDOT2(bc_h2(hv.y), bc_h2(wv.y), yacc);
        yacc = FDOT2(bc_h2(hv.z), bc_h2(wv.z), yacc);
        yacc = FDOT2(bc_h2(hv.w), bc_h2(wv.w), yacc);
      }
      yacc += __shfl_xor(yacc, 16, 64);
      yacc += __shfl_xor(yacc, 32, 64);
      if (uc == 0)
        __builtin_nontemporal_store(yacc + ybias,
            &out[(size_t)(b0 + bb2) * (TT * OO) + (size_t)(it - 1) * OO + (s * 8 + wave)]);
    }

    // ---- x prefetch for it+1 (independent of h; issue before barrier) ----
    uint4 xr0, xr1;
    const bool xok = (it + 1 < TT);
    if (xok) {
      const ushort* xs = x16 + ((size_t)(b0 + sbb) * TT + (it + 1)) * II + sc5 * 16;
      xr0 = *(const uint4*)xs;
      xr1 = *(const uint4*)(xs + 8);
    }
    __syncthreads();

    // ---- reduce + state update (waves 0-3) ----
    if (it < TT && wave < 4) {
      const int bb = tid & 15, ul = tid >> 4;
      float t0 = 0.f, t1 = 0.f, t2 = 0.f, t3 = 0.f;
      #pragma unroll
      for (int w = 0; w < 8; ++w) {
        t0 += part[(w * 64 + ul * 4 + 0) * 17 + bb];
        t1 += part[(w * 64 + ul * 4 + 1) * 17 + bb];
        t2 += part[(w * 64 + ul * 4 + 2) * 17 + bb];
        t3 += part[(w * 64 + ul * 4 + 3) * 17 + bb];
      }
      float gf = sigm(t0 + bsf);
      float gi = sigm(t1 + bsi);
      float gc = tanh_c(t2 + bsc);
      float go = sigm(t3 + bso);
      cstate = gf * cstate + gi * gc;
      float hv = go * tanh_c(cstate);

      uint32_t hu = (uint32_t)__builtin_bit_cast(unsigned short, (_Float16)hv);
      uint32_t other = (uint32_t)__shfl_down((int)hu, 16, 64);
      if ((ul & 1) == 0) {
        ushort* hp = hb16 + (size_t)((it + 1) & 1) * BH
                   + (size_t)(b0 + bb) * HH + (u0 + ul);
        cohere_st4(hp, hu | (other << 16));
      }
      if (it == TT - 1) {
        out[(size_t)BTO + (size_t)(b0 + bb) * HH + (u0 + ul)] = hv;
        out[(size_t)BTO + BH + (size_t)(b0 + bb) * HH + (u0 + ul)] = cstate;
      }
    }

    if (it < TT) {
      // write x-part for it+1 (acts reads finished at the syncthreads above)
      if (xok) {
        acts4[sbb * 193 + sc5 * 2]     = xr0;
        acts4[sbb * 193 + sc5 * 2 + 1] = xr1;
      }
      // group barrier (h stores visible before signal)
      asm volatile("s_waitcnt vmcnt(0)" ::: "memory");
      __syncthreads();
      if (tid == 0) {
        uint32_t old = __hip_atomic_fetch_add(subp, 1u, __ATOMIC_RELAXED, __HIP_MEMORY_SCOPE_AGENT);
        if ((old & 7u) == 7u)
          __hip_atomic_fetch_add(rootp, 1u, __ATOMIC_RELAXED, __HIP_MEMORY_SCOPE_AGENT);
        while (__hip_atomic_load(rootp, __ATOMIC_RELAXED, __HIP_MEMORY_SCOPE_AGENT)
               < 8u * (uint32_t)(it + 1))
          __builtin_amdgcn_s_sleep(2);
      }
      __syncthreads();
      // h gather for it+1 (h_it, slot (it+1)&1)
      {
        const ushort* hs = hb16 + (size_t)((it + 1) & 1) * BH
                         + (size_t)(b0 + sbb) * HH + sc5 * 32;
        uint2 q[8];
        #pragma unroll
        for (int j = 0; j < 8; ++j) q[j] = cohere_ld8(hs + j * 4);
        #pragma unroll
        for (int j = 0; j < 4; ++j)
          acts4[sbb * 193 + 64 + sc5 * 4 + j] =
              make_uint4(q[2*j].x, q[2*j].y, q[2*j+1].x, q[2*j+1].y);
      }
      __syncthreads();
    }
  }
}

extern "C" void kernel_launch(void* const* d_in, const int* in_sizes, int n_in,
                              void* d_out, int out_size, void* d_ws, size_t ws_size,
                              hipStream_t stream) {
  (void)in_sizes; (void)n_in; (void)out_size; (void)ws_size;
  const float* x   = (const float*)d_in[0];
  const float* Wf  = (const float*)d_in[1];
  const float* bf  = (const float*)d_in[2];
  const float* Wi  = (const float*)d_in[3];
  const float* bi  = (const float*)d_in[4];
  const float* Wc  = (const float*)d_in[5];
  const float* bc  = (const float*)d_in[6];
  const float* Wo  = (const float*)d_in[7];
  const float* bo  = (const float*)d_in[8];
  const float* Wfc = (const float*)d_in[9];
  const float* bfc = (const float*)d_in[10];
  float* out = (float*)d_out;
  float* ws  = (float*)d_ws;

  // zero barrier counters + h slot 0 (h0 = 0); deterministic per call
  hipMemsetAsync(d_ws, 0, (size_t)(WS_HBUF + BH / 2) * sizeof(float), stream);

  // pack fp16 slab + Wfc + x
  const int nprep = SS * NKOCT * 64 + 512 * 128 + (BB * TT * II) / 8;
  prep<<<dim3((nprep + 255) / 256), dim3(256), 0, stream>>>(Wf, Wi, Wc, Wo, Wfc, x, ws);

  hipFuncSetAttribute((const void*)lstm_kernel,
                      hipFuncAttributeMaxDynamicSharedMemorySize, L_TOTAL_BYTES);

  void* args[] = { &bf, &bi, &bc, &bo, &bfc, &out, &ws };
  hipLaunchCooperativeKernel(reinterpret_cast<void*>(lstm_kernel),
                             dim3(NBLK), dim3(NTHR), args,
                             (unsigned)L_TOTAL_BYTES, stream);
}

// Round 12
// 4566.252 us; speedup vs baseline: 3.2355x; 3.2355x over previous
//
#include <hip/hip_runtime.h>
#include <stdint.h>

#define BB 64
#define TT 512
#define II 512
#define HH 1024
#define OO 512
#define NBLK 256
#define NTHR 256
#define NB 16            // batches per group
#define US 16            // units per slice

// ws float-offsets
#define WS_HBUF  1280                      // 2 slots x 64x1024 fp16 = 65536 floats
#define WS_ASLAB 66816                     // 64s x 4mt x 48ks x 64ln uint4
#define WS_YSLAB 3212544                   // 64s x 32ks x 64ln uint4
#define BTO (BB*TT*OO)
#define BH  (BB*HH)

// LDS: acts [192 koct][16 batch] uint4 (49152 B) + ypart [4][64][4] f32 (4096 B)
#define L_YP_F 12288
#define L_BYTES ((12288 + 1024) * 4)       // 53248

typedef __fp16 v8hf __attribute__((ext_vector_type(8)));   // MFMA operand type
typedef float f32x4 __attribute__((ext_vector_type(4)));
typedef _Float16 h2 __attribute__((ext_vector_type(2)));

static __device__ __forceinline__ v8hf bc8(uint4 v) { return __builtin_bit_cast(v8hf, v); }
static __device__ __forceinline__ uint32_t pk_u32(float a, float b) {
  return __builtin_bit_cast(uint32_t, __builtin_amdgcn_cvt_pkrtz(a, b));
}

// acts addressing: koct = fp16-octet index (x: 0..63, h: 64..191), b = batch.
// [blk=koct>>2][off] with off = (koct&3)*16 + (b ^ (blk&7)):
// MFMA B-reads are contiguous 64-uint4 blocks (conflict-free ds_read_b128);
// the XOR spreads staging writes across banks.
static __device__ __forceinline__ int aidx(int koct, int b) {
  int blk = koct >> 2;
  return blk * 64 + (koct & 3) * 16 + (b ^ (blk & 7));
}

__device__ __forceinline__ float sigm(float v) { return 1.0f / (1.0f + __expf(-v)); }
__device__ __forceinline__ float tanh_c(float v) {
  v = fminf(fmaxf(v, -20.0f), 20.0f);
  float e = __expf(-2.0f * v);
  return (1.0f - e) / (1.0f + e);
}

// agent-scope (sc0 sc1): per-access coherence, NO cache-wide ops
__device__ __forceinline__ uint2 cohere_ld8(const void* p) {
  unsigned long long q = __hip_atomic_load((const unsigned long long*)p,
                                           __ATOMIC_RELAXED, __HIP_MEMORY_SCOPE_AGENT);
  return __builtin_bit_cast(uint2, q);
}
__device__ __forceinline__ void cohere_st8(void* p, uint32_t lo, uint32_t hi) {
  uint2 v = make_uint2(lo, hi);
  __hip_atomic_store((unsigned long long*)p, __builtin_bit_cast(unsigned long long, v),
                     __ATOMIC_RELAXED, __HIP_MEMORY_SCOPE_AGENT);
}

// -------- prep: pack A-slab (gate weights, MFMA A-frag order) + y-slab --------
__global__ void __launch_bounds__(256) prep(
    const float* __restrict__ Wf, const float* __restrict__ Wi,
    const float* __restrict__ Wc, const float* __restrict__ Wo,
    const float* __restrict__ Wfc, float* __restrict__ ws)
{
  const int NA = 64 * 4 * 48 * 64;
  const int NY = 64 * 32 * 64;
  int idx = blockIdx.x * 256 + threadIdx.x;
  if (idx < NA) {
    int s = idx / (4 * 48 * 64);
    int rem = idx % (4 * 48 * 64);
    int mt = rem / (48 * 64);
    int rem2 = rem % (48 * 64);
    int ks = rem2 >> 6, ln = rem2 & 63;
    int r = ln & 15, kq = ln >> 4;
    int unit = s * 16 + mt * 4 + (r >> 2), gate = r & 3;
    const float* W = (gate == 0) ? Wf : (gate == 1) ? Wi : (gate == 2) ? Wc : Wo;
    const float* src = W + (size_t)unit * 1536 + ks * 32 + kq * 8;
    uint32_t p[4];
    #pragma unroll
    for (int j = 0; j < 4; ++j) {
      h2 t; t.x = (_Float16)src[2*j]; t.y = (_Float16)src[2*j+1];   // RNE
      p[j] = __builtin_bit_cast(uint32_t, t);
    }
    ((uint4*)(ws + WS_ASLAB))[idx] = make_uint4(p[0], p[1], p[2], p[3]);
  } else if (idx < NA + NY) {
    int j2 = idx - NA;
    int s = j2 / (32 * 64);
    int rem = j2 % (32 * 64);
    int ks = rem >> 6, ln = rem & 63;
    int r = ln & 15, kq = ln >> 4;
    uint4 outv = make_uint4(0, 0, 0, 0);
    if (r < 8) {
      const float* src = Wfc + (size_t)(s * 8 + r) * 1024 + ks * 32 + kq * 8;
      uint32_t p[4];
      #pragma unroll
      for (int j = 0; j < 4; ++j) {
        h2 t; t.x = (_Float16)src[2*j]; t.y = (_Float16)src[2*j+1];
        p[j] = __builtin_bit_cast(uint32_t, t);
      }
      outv = make_uint4(p[0], p[1], p[2], p[3]);
    }
    ((uint4*)(ws + WS_YSLAB))[j2] = outv;
  }
}

__global__ void __launch_bounds__(NTHR, 1)
lstm_kernel(const float* __restrict__ x,
            const float* __restrict__ bf, const float* __restrict__ bi,
            const float* __restrict__ bc, const float* __restrict__ bo,
            const float* __restrict__ bfc,
            float* __restrict__ out, float* __restrict__ ws)
{
  extern __shared__ float ldsf[];
  uint4* acts4 = (uint4*)ldsf;               // [192][16] via aidx
  float* ypart = ldsf + L_YP_F;              // [4 waves][64 lanes][4]

  const int tid  = threadIdx.x;
  const int blk  = blockIdx.x;
  const int wave = tid >> 6;                 // == m-tile
  const int lane = tid & 63;
  const int g = blk >> 6, s = blk & 63;
  const int b0 = g * NB;
  const int u0 = s * US;

  uint32_t* ctrl  = (uint32_t*)ws;
  uint32_t* rootp = ctrl + g * 32;
  uint32_t* subp  = ctrl + 128 + (g * 8 + (s & 7)) * 32;
  ushort* hb16 = (ushort*)(ws + WS_HBUF);

  const int bq = lane & 15, kq = lane >> 4;  // B-col/batch ; k-group & C row-quad
  const int sb = tid >> 4, sj = tid & 15;    // staging: batch, 1/16 of row

  // ---- persistent A fragments: Aw (gate) + Yw (this wave's Wfc k-slice) ----
  v8hf Aw[48];
  v8hf Yw[8];
  {
    const uint4* wpA = (const uint4*)(ws + WS_ASLAB) + ((size_t)(s * 4 + wave) * 48) * 64 + lane;
    #pragma unroll
    for (int k = 0; k < 48; ++k) Aw[k] = bc8(wpA[k * 64]);
    const uint4* wpY = (const uint4*)(ws + WS_YSLAB) + ((size_t)(s * 32 + wave * 8)) * 64 + lane;
    #pragma unroll
    for (int k = 0; k < 8; ++k) Yw[k] = bc8(wpY[k * 64]);
  }
  const int unit = u0 + wave * 4 + kq;
  const float bsf = bf[unit], bsi = bi[unit], bsc = bc[unit], bso = bo[unit];
  const float ybias = (tid < 128) ? bfc[s * 8 + (tid >> 4)] : 0.0f;
  float cstate = 0.0f;

  // ---- initial staging: x_0 + h_{-1}(=0, slot 0 zeroed) ----
  {
    const float* xs = x + ((size_t)(b0 + sb) * TT + 0) * II + sj * 32;
    #pragma unroll
    for (int v = 0; v < 4; ++v) {
      float4 u = ((const float4*)xs)[2*v], w = ((const float4*)xs)[2*v+1];
      acts4[aidx(sj * 4 + v, sb)] =
          make_uint4(pk_u32(u.x,u.y), pk_u32(u.z,u.w), pk_u32(w.x,w.y), pk_u32(w.z,w.w));
    }
    const ushort* hs = hb16 + (size_t)(b0 + sb) * HH + sj * 64;
    #pragma unroll
    for (int wv = 0; wv < 8; ++wv) {
      uint2 q0 = cohere_ld8(hs + wv * 8), q1 = cohere_ld8(hs + wv * 8 + 4);
      acts4[aidx(64 + sj * 8 + wv, sb)] = make_uint4(q0.x, q0.y, q1.x, q1.y);
    }
  }
  __syncthreads();

  for (int it = 0; it <= TT; ++it) {
    // ---- x prefetch for it+1 (regs; written to LDS after S1) ----
    float4 xr[8];
    const bool xok = (it + 1 < TT);
    if (xok) {
      const float* xs = x + ((size_t)(b0 + sb) * TT + (it + 1)) * II + sj * 32;
      #pragma unroll
      for (int v = 0; v < 8; ++v) xr[v] = ((const float4*)xs)[v];
    }

    // ---- gate MFMA ----
    float4 tg;
    if (it < TT) {
      f32x4 ac[4];
      #pragma unroll
      for (int j = 0; j < 4; ++j) ac[j] = (f32x4){0.f, 0.f, 0.f, 0.f};
      #pragma unroll
      for (int ks = 0; ks < 48; ++ks) {
        uint4 bv = acts4[ks * 64 + kq * 16 + (bq ^ (ks & 7))];
        ac[ks & 3] = __builtin_amdgcn_mfma_f32_16x16x32_f16(Aw[ks], bc8(bv), ac[ks & 3], 0, 0, 0);
      }
      f32x4 t = (ac[0] + ac[1]) + (ac[2] + ac[3]);
      tg = make_float4(t[0], t[1], t[2], t[3]);
    }

    // ---- y partial MFMA (k-slice of Wfc), partials to LDS ----
    if (it > 0) {
      f32x4 yc = (f32x4){0.f, 0.f, 0.f, 0.f};
      #pragma unroll
      for (int k = 0; k < 8; ++k) {
        int yblk = 16 + wave * 8 + k;
        uint4 bv = acts4[yblk * 64 + kq * 16 + (bq ^ (yblk & 7))];
        yc = __builtin_amdgcn_mfma_f32_16x16x32_f16(Yw[k], bc8(bv), yc, 0, 0, 0);
      }
      float* yp = ypart + (wave * 64 + lane) * 4;
      yp[0] = yc[0]; yp[1] = yc[1]; yp[2] = yc[2]; yp[3] = yc[3];
    }
    __syncthreads();                         // S1: acts reads done, ypart ready

    // ---- y finalize: 128 threads, one (batch, out-col) each ----
    if (it > 0 && tid < 128) {
      int fb = tid & 15, rr = tid >> 4;      // rr = 0..7 -> o = s*8+rr
      int l = (rr >> 2) * 16 + fb;           // source lane (kq=rr>>2, bq=fb)
      float yv = ybias;
      #pragma unroll
      for (int w = 0; w < 4; ++w) yv += ypart[(w * 64 + l) * 4 + (rr & 3)];
      out[(size_t)(b0 + fb) * (TT * OO) + (size_t)(it - 1) * OO + s * 8 + rr] = yv;
    }

    if (it < TT) {
      // ---- write x-part for it+1 ----
      if (xok) {
        #pragma unroll
        for (int v = 0; v < 4; ++v)
          acts4[aidx(sj * 4 + v, sb)] =
              make_uint4(pk_u32(xr[2*v].x, xr[2*v].y), pk_u32(xr[2*v].z, xr[2*v].w),
                         pk_u32(xr[2*v+1].x, xr[2*v+1].y), pk_u32(xr[2*v+1].z, xr[2*v+1].w));
      }

      // ---- state update (every lane owns (unit, bq)) + packed h store ----
      {
        float gf = sigm(tg.x + bsf);
        float gi = sigm(tg.y + bsi);
        float gc = tanh_c(tg.z + bsc);
        float go = sigm(tg.w + bso);
        cstate = gf * cstate + gi * gc;
        float hv = go * tanh_c(cstate);

        uint32_t hu = (uint32_t)__builtin_bit_cast(unsigned short, (_Float16)hv);
        uint32_t pA  = hu | ((uint32_t)__shfl_down((int)hu, 16) << 16);  // units q,q+1
        uint32_t hiw = (uint32_t)__shfl_down((int)pA, 32);               // units q+2,q+3
        if (kq == 0) {
          ushort* hp = hb16 + (size_t)((it + 1) & 1) * BH
                     + (size_t)(b0 + bq) * HH + (u0 + wave * 4);
          cohere_st8(hp, pA, hiw);
        }
        if (it == TT - 1) {
          out[(size_t)BTO + (size_t)(b0 + bq) * HH + unit] = hv;
          out[(size_t)BTO + BH + (size_t)(b0 + bq) * HH + unit] = cstate;
        }
      }

      // ---- group barrier ----
      asm volatile("s_waitcnt vmcnt(0)" ::: "memory");
      __syncthreads();                       // S2
      if (tid == 0) {
        uint32_t old = __hip_atomic_fetch_add(subp, 1u, __ATOMIC_RELAXED, __HIP_MEMORY_SCOPE_AGENT);
        if ((old & 7u) == 7u)
          __hip_atomic_fetch_add(rootp, 1u, __ATOMIC_RELAXED, __HIP_MEMORY_SCOPE_AGENT);
        while (__hip_atomic_load(rootp, __ATOMIC_RELAXED, __HIP_MEMORY_SCOPE_AGENT)
               < 8u * (uint32_t)(it + 1))
          __builtin_amdgcn_s_sleep(1);
      }
      __syncthreads();                       // S3

      // ---- gather h_it -> acts h-part ----
      {
        const ushort* hs = hb16 + (size_t)((it + 1) & 1) * BH
                         + (size_t)(b0 + sb) * HH + sj * 64;
        uint2 q[16];
        #pragma unroll
        for (int m = 0; m < 16; ++m) q[m] = cohere_ld8(hs + m * 4);
        #pragma unroll
        for (int wv = 0; wv < 8; ++wv)
          acts4[aidx(64 + sj * 8 + wv, sb)] =
              make_uint4(q[2*wv].x, q[2*wv].y, q[2*wv+1].x, q[2*wv+1].y);
      }
      __syncthreads();                       // S4: acts ready for it+1
    }
  }
}

extern "C" void kernel_launch(void* const* d_in, const int* in_sizes, int n_in,
                              void* d_out, int out_size, void* d_ws, size_t ws_size,
                              hipStream_t stream) {
  (void)in_sizes; (void)n_in; (void)out_size; (void)ws_size;
  const float* x   = (const float*)d_in[0];
  const float* Wf  = (const float*)d_in[1];
  const float* bf  = (const float*)d_in[2];
  const float* Wi  = (const float*)d_in[3];
  const float* bi  = (const float*)d_in[4];
  const float* Wc  = (const float*)d_in[5];
  const float* bc  = (const float*)d_in[6];
  const float* Wo  = (const float*)d_in[7];
  const float* bo  = (const float*)d_in[8];
  const float* Wfc = (const float*)d_in[9];
  const float* bfc = (const float*)d_in[10];
  float* out = (float*)d_out;
  float* ws  = (float*)d_ws;

  // zero barrier counters + h slot 0 (h0 = 0); deterministic per call
  (void)hipMemsetAsync(d_ws, 0, (size_t)(WS_HBUF + BH / 2) * sizeof(float), stream);

  // pack fp16 MFMA fragment slabs
  const int nprep = 64 * 4 * 48 * 64 + 64 * 32 * 64;
  prep<<<dim3((nprep + 255) / 256), dim3(256), 0, stream>>>(Wf, Wi, Wc, Wo, Wfc, ws);

  // PLAIN launch (not cooperative): the grid barrier is hand-rolled atomics,
  // so cooperative-launch validation (suspected round-11 silent rejection) is
  // unnecessary. 256 blocks <= 256 CUs at >=1 block/CU => all co-resident.
  lstm_kernel<<<dim3(NBLK), dim3(NTHR), L_BYTES, stream>>>(
      x, bf, bi, bc, bo, bfc, out, ws);
}

// Round 13
// 3876.818 us; speedup vs baseline: 3.8109x; 1.1778x over previous
//
#include <hip/hip_runtime.h>
#include <stdint.h>

#define BB 64
#define TT 512
#define II 512
#define HH 1024
#define OO 512
#define NBLK 256
#define NTHR 256
#define NB 16            // batches per group
#define US 16            // units per slice

// ws float-offsets
#define WS_HBUF  1280                      // 2 slots x 64x1024 fp16 = 65536 floats
#define WS_ASLAB 66816                     // 64s x 4mt x 48ks x 64ln uint4
#define WS_YSLAB 3212544                   // 64s x 32ks x 64ln uint4
#define BTO (BB*TT*OO)
#define BH  (BB*HH)

// LDS: x-acts [64 koct][16] uint4 (16KB) | h-acts [128 koct][16] uint4 (32KB)
//      | ypart [4][64][4] f32 (4KB)
#define L_HB_U4 1024                       // uint4 index of h region
#define L_YP_F  12288                      // float index of ypart
#define L_BYTES ((12288 + 1024) * 4)       // 53248

typedef __fp16 v8hf __attribute__((ext_vector_type(8)));   // MFMA operand type
typedef float f32x4 __attribute__((ext_vector_type(4)));
typedef _Float16 h2 __attribute__((ext_vector_type(2)));

static __device__ __forceinline__ v8hf bc8(uint4 v) { return __builtin_bit_cast(v8hf, v); }
static __device__ __forceinline__ uint32_t pk_u32(float a, float b) {
  return __builtin_bit_cast(uint32_t, __builtin_amdgcn_cvt_pkrtz(a, b));
}

__device__ __forceinline__ float sigm(float v) { return 1.0f / (1.0f + __expf(-v)); }
__device__ __forceinline__ float tanh_c(float v) {
  v = fminf(fmaxf(v, -20.0f), 20.0f);
  float e = __expf(-2.0f * v);
  return (1.0f - e) / (1.0f + e);
}

// agent-scope (sc0 sc1): per-access coherence, NO cache-wide ops
__device__ __forceinline__ uint2 cohere_ld8(const void* p) {
  unsigned long long q = __hip_atomic_load((const unsigned long long*)p,
                                           __ATOMIC_RELAXED, __HIP_MEMORY_SCOPE_AGENT);
  return __builtin_bit_cast(uint2, q);
}
__device__ __forceinline__ void cohere_st8(void* p, uint32_t lo, uint32_t hi) {
  uint2 v = make_uint2(lo, hi);
  __hip_atomic_store((unsigned long long*)p, __builtin_bit_cast(unsigned long long, v),
                     __ATOMIC_RELAXED, __HIP_MEMORY_SCOPE_AGENT);
}

// -------- prep: pack A-slab (gate weights, MFMA A-frag order) + y-slab --------
__global__ void __launch_bounds__(256) prep(
    const float* __restrict__ Wf, const float* __restrict__ Wi,
    const float* __restrict__ Wc, const float* __restrict__ Wo,
    const float* __restrict__ Wfc, float* __restrict__ ws)
{
  const int NA = 64 * 4 * 48 * 64;
  const int NY = 64 * 32 * 64;
  int idx = blockIdx.x * 256 + threadIdx.x;
  if (idx < NA) {
    int s = idx / (4 * 48 * 64);
    int rem = idx % (4 * 48 * 64);
    int mt = rem / (48 * 64);
    int rem2 = rem % (48 * 64);
    int ks = rem2 >> 6, ln = rem2 & 63;
    int r = ln & 15, kq = ln >> 4;
    int unit = s * 16 + mt * 4 + (r >> 2), gate = r & 3;
    const float* W = (gate == 0) ? Wf : (gate == 1) ? Wi : (gate == 2) ? Wc : Wo;
    const float* src = W + (size_t)unit * 1536 + ks * 32 + kq * 8;
    uint32_t p[4];
    #pragma unroll
    for (int j = 0; j < 4; ++j) {
      h2 t; t.x = (_Float16)src[2*j]; t.y = (_Float16)src[2*j+1];   // RNE
      p[j] = __builtin_bit_cast(uint32_t, t);
    }
    ((uint4*)(ws + WS_ASLAB))[idx] = make_uint4(p[0], p[1], p[2], p[3]);
  } else if (idx < NA + NY) {
    int j2 = idx - NA;
    int s = j2 / (32 * 64);
    int rem = j2 % (32 * 64);
    int ks = rem >> 6, ln = rem & 63;
    int r = ln & 15, kq = ln >> 4;
    uint4 outv = make_uint4(0, 0, 0, 0);
    if (r < 8) {
      const float* src = Wfc + (size_t)(s * 8 + r) * 1024 + ks * 32 + kq * 8;
      uint32_t p[4];
      #pragma unroll
      for (int j = 0; j < 4; ++j) {
        h2 t; t.x = (_Float16)src[2*j]; t.y = (_Float16)src[2*j+1];
        p[j] = __builtin_bit_cast(uint32_t, t);
      }
      outv = make_uint4(p[0], p[1], p[2], p[3]);
    }
    ((uint4*)(ws + WS_YSLAB))[j2] = outv;
  }
}

__global__ void __launch_bounds__(NTHR, 1)
lstm_kernel(const float* __restrict__ x,
            const float* __restrict__ bf, const float* __restrict__ bi,
            const float* __restrict__ bc, const float* __restrict__ bo,
            const float* __restrict__ bfc,
            float* __restrict__ out, float* __restrict__ ws)
{
  extern __shared__ float ldsf[];
  uint4* acts4 = (uint4*)ldsf;               // x: [0,1024) ; h: [1024,3072)
  float* ypart = ldsf + L_YP_F;              // [4 waves][64 lanes][4]

  const int tid  = threadIdx.x;
  const int blk  = blockIdx.x;
  const int wave = tid >> 6;                 // == m-tile
  const int lane = tid & 63;
  const int g = blk >> 6, s = blk & 63;
  const int b0 = g * NB;
  const int u0 = s * US;

  uint32_t* ctrl  = (uint32_t*)ws;
  uint32_t* rootp = ctrl + g * 32;
  uint32_t* subp  = ctrl + 128 + (g * 8 + (s & 7)) * 32;
  ushort* hb16 = (ushort*)(ws + WS_HBUF);

  const int bq = lane & 15, kq = lane >> 4;  // B-col/batch ; k-group & C row-quad
  const int sb = tid >> 4, sj = tid & 15;    // staging: batch, 1/16 of row

  // ---- persistent A fragments: Aw (gate; ks 0..15 = x, 16..47 = h) + Yw ----
  v8hf Aw[48];
  v8hf Yw[8];
  {
    const uint4* wpA = (const uint4*)(ws + WS_ASLAB) + ((size_t)(s * 4 + wave) * 48) * 64 + lane;
    #pragma unroll
    for (int k = 0; k < 48; ++k) Aw[k] = bc8(wpA[k * 64]);
    const uint4* wpY = (const uint4*)(ws + WS_YSLAB) + ((size_t)(s * 32 + wave * 8)) * 64 + lane;
    #pragma unroll
    for (int k = 0; k < 8; ++k) Yw[k] = bc8(wpY[k * 64]);
  }
  const int unit = u0 + wave * 4 + kq;
  const float bsf = bf[unit], bsi = bi[unit], bsc = bc[unit], bso = bo[unit];
  const float ybias = (tid < 128) ? bfc[s * 8 + (tid >> 4)] : 0.0f;
  float cstate = 0.0f;
  f32x4 xacc[4];                             // x-part gate partials for step it

  // ---- prologue: stage x_0 ; zero h-LDS (h_{-1}=0) ; compute xacc(0) ----
  {
    const float* xs = x + ((size_t)(b0 + sb) * TT + 0) * II + sj * 32;
    #pragma unroll
    for (int v = 0; v < 4; ++v) {
      float4 u = ((const float4*)xs)[2*v], w = ((const float4*)xs)[2*v+1];
      acts4[sj * 64 + v * 16 + (sb ^ (sj & 7))] =
          make_uint4(pk_u32(u.x,u.y), pk_u32(u.z,u.w), pk_u32(w.x,w.y), pk_u32(w.z,w.w));
    }
    #pragma unroll
    for (int w = 0; w < 8; ++w) {
      int khb = sj * 2 + (w >> 2);
      acts4[L_HB_U4 + khb * 64 + (w & 3) * 16 + (sb ^ (khb & 7))] = make_uint4(0,0,0,0);
    }
  }
  __syncthreads();
  {
    #pragma unroll
    for (int j = 0; j < 4; ++j) xacc[j] = (f32x4){0.f, 0.f, 0.f, 0.f};
    #pragma unroll
    for (int ks = 0; ks < 16; ++ks) {
      uint4 bv = acts4[ks * 64 + kq * 16 + (bq ^ (ks & 7))];
      xacc[ks & 3] = __builtin_amdgcn_mfma_f32_16x16x32_f16(Aw[ks], bc8(bv), xacc[ks & 3], 0, 0, 0);
    }
  }

  for (int it = 0; it <= TT; ++it) {
    // ---- P0: x prefetch for it+1 (regs) ----
    float4 xr[8];
    const bool xok = (it + 1 < TT);
    if (xok) {
      const float* xs = x + ((size_t)(b0 + sb) * TT + (it + 1)) * II + sj * 32;
      #pragma unroll
      for (int v = 0; v < 8; ++v) xr[v] = ((const float4*)xs)[v];
    }

    if (it < TT) {
      // ---- P1: gate h-MFMA (32 k-steps over h_{it-1}) + xacc(it) ----
      f32x4 ac[4];
      #pragma unroll
      for (int j = 0; j < 4; ++j) ac[j] = xacc[j];
      #pragma unroll
      for (int ksh = 0; ksh < 32; ++ksh) {
        uint4 bv = acts4[L_HB_U4 + ksh * 64 + kq * 16 + (bq ^ (ksh & 7))];
        ac[ksh & 3] = __builtin_amdgcn_mfma_f32_16x16x32_f16(Aw[16 + ksh], bc8(bv), ac[ksh & 3], 0, 0, 0);
      }
      f32x4 t = (ac[0] + ac[1]) + (ac[2] + ac[3]);

      // ---- P2: state update + packed h store (ring slot (it+1)&1) ----
      float gf = sigm(t[0] + bsf);
      float gi = sigm(t[1] + bsi);
      float gc = tanh_c(t[2] + bsc);
      float go = sigm(t[3] + bso);
      cstate = gf * cstate + gi * gc;
      float hv = go * tanh_c(cstate);

      uint32_t hu = (uint32_t)__builtin_bit_cast(unsigned short, (_Float16)hv);
      uint32_t pA  = hu | ((uint32_t)__shfl_down((int)hu, 16) << 16);  // units q,q+1
      uint32_t hiw = (uint32_t)__shfl_down((int)pA, 32);               // units q+2,q+3
      if (kq == 0) {
        ushort* hp = hb16 + (size_t)((it + 1) & 1) * BH
                   + (size_t)(b0 + bq) * HH + (u0 + wave * 4);
        cohere_st8(hp, pA, hiw);
      }
      if (it == TT - 1) {
        out[(size_t)BTO + (size_t)(b0 + bq) * HH + unit] = hv;
        out[(size_t)BTO + BH + (size_t)(b0 + bq) * HH + unit] = cstate;
      }

      // ---- S_b + ARRIVE (fire-and-forget) ----
      asm volatile("s_waitcnt vmcnt(0)" ::: "memory");
      __syncthreads();
      if (tid == 0) {
        uint32_t old = __hip_atomic_fetch_add(subp, 1u, __ATOMIC_RELAXED, __HIP_MEMORY_SCOPE_AGENT);
        if ((old & 7u) == 7u)
          __hip_atomic_fetch_add(rootp, 1u, __ATOMIC_RELAXED, __HIP_MEMORY_SCOPE_AGENT);
      }
    }

    // ======== barrier shadow: everything h_it-independent ========

    // ---- P3: y-MFMA for y_{it-1} (h_{it-1} still in h-LDS) ----
    if (it > 0) {
      f32x4 yc = (f32x4){0.f, 0.f, 0.f, 0.f};
      #pragma unroll
      for (int k = 0; k < 8; ++k) {
        int ksh = wave * 8 + k;
        uint4 bv = acts4[L_HB_U4 + ksh * 64 + kq * 16 + (bq ^ (ksh & 7))];
        yc = __builtin_amdgcn_mfma_f32_16x16x32_f16(Yw[k], bc8(bv), yc, 0, 0, 0);
      }
      float* yp = ypart + (wave * 64 + lane) * 4;
      yp[0] = yc[0]; yp[1] = yc[1]; yp[2] = yc[2]; yp[3] = yc[3];
    }

    // ---- P4: write x_{it+1} into x-LDS ----
    if (xok) {
      #pragma unroll
      for (int v = 0; v < 4; ++v)
        acts4[sj * 64 + v * 16 + (sb ^ (sj & 7))] =
            make_uint4(pk_u32(xr[2*v].x, xr[2*v].y), pk_u32(xr[2*v].z, xr[2*v].w),
                       pk_u32(xr[2*v+1].x, xr[2*v+1].y), pk_u32(xr[2*v+1].z, xr[2*v+1].w));
    }
    __syncthreads();                         // S_c: ypart + x-LDS ready

    // ---- y finalize: 128 threads, one (batch, out-col) each ----
    if (it > 0 && tid < 128) {
      int fb = tid & 15, rr = tid >> 4;      // rr = 0..7 -> o = s*8+rr
      int l = (rr >> 2) * 16 + fb;           // source lane (kq=rr>>2, bq=fb)
      float yv = ybias;
      #pragma unroll
      for (int w = 0; w < 4; ++w) yv += ypart[(w * 64 + l) * 4 + (rr & 3)];
      out[(size_t)(b0 + fb) * (TT * OO) + (size_t)(it - 1) * OO + s * 8 + rr] = yv;
    }

    // ---- P5: x-part gate MFMA for step it+1 ----
    if (xok) {
      #pragma unroll
      for (int j = 0; j < 4; ++j) xacc[j] = (f32x4){0.f, 0.f, 0.f, 0.f};
      #pragma unroll
      for (int ks = 0; ks < 16; ++ks) {
        uint4 bv = acts4[ks * 64 + kq * 16 + (bq ^ (ks & 7))];
        xacc[ks & 3] = __builtin_amdgcn_mfma_f32_16x16x32_f16(Aw[ks], bc8(bv), xacc[ks & 3], 0, 0, 0);
      }
    }

    if (it < TT) {
      // ---- WAIT: poll root until all arrivals for this step ----
      if (tid == 0) {
        while (__hip_atomic_load(rootp, __ATOMIC_RELAXED, __HIP_MEMORY_SCOPE_AGENT)
               < 8u * (uint32_t)(it + 1))
          __builtin_amdgcn_s_sleep(1);
      }
      __syncthreads();                       // S_w

      // ---- P6: gather h_it -> h-LDS ----
      {
        const ushort* hs = hb16 + (size_t)((it + 1) & 1) * BH
                         + (size_t)(b0 + sb) * HH + sj * 64;
        uint2 q[16];
        #pragma unroll
        for (int m = 0; m < 16; ++m) q[m] = cohere_ld8(hs + m * 4);
        #pragma unroll
        for (int w = 0; w < 8; ++w) {
          int khb = sj * 2 + (w >> 2);
          acts4[L_HB_U4 + khb * 64 + (w & 3) * 16 + (sb ^ (khb & 7))] =
              make_uint4(q[2*w].x, q[2*w].y, q[2*w+1].x, q[2*w+1].y);
        }
      }
      __syncthreads();                       // S_d: h ready for it+1
    }
  }
}

extern "C" void kernel_launch(void* const* d_in, const int* in_sizes, int n_in,
                              void* d_out, int out_size, void* d_ws, size_t ws_size,
                              hipStream_t stream) {
  (void)in_sizes; (void)n_in; (void)out_size; (void)ws_size;
  const float* x   = (const float*)d_in[0];
  const float* Wf  = (const float*)d_in[1];
  const float* bf  = (const float*)d_in[2];
  const float* Wi  = (const float*)d_in[3];
  const float* bi  = (const float*)d_in[4];
  const float* Wc  = (const float*)d_in[5];
  const float* bc  = (const float*)d_in[6];
  const float* Wo  = (const float*)d_in[7];
  const float* bo  = (const float*)d_in[8];
  const float* Wfc = (const float*)d_in[9];
  const float* bfc = (const float*)d_in[10];
  float* out = (float*)d_out;
  float* ws  = (float*)d_ws;

  // zero barrier counters; h slots are written before any read
  (void)hipMemsetAsync(d_ws, 0, (size_t)WS_HBUF * sizeof(float), stream);

  // pack fp16 MFMA fragment slabs
  const int nprep = 64 * 4 * 48 * 64 + 64 * 32 * 64;
  prep<<<dim3((nprep + 255) / 256), dim3(256), 0, stream>>>(Wf, Wi, Wc, Wo, Wfc, ws);

  // plain launch; 256 blocks <= 256 CUs => all co-resident for the spin barrier
  lstm_kernel<<<dim3(NBLK), dim3(NTHR), L_BYTES, stream>>>(
      x, bf, bi, bc, bo, bfc, out, ws);
}

// Round 14
// 3736.660 us; speedup vs baseline: 3.9539x; 1.0375x over previous
//
#include <hip/hip_runtime.h>
#include <stdint.h>

#define BB 64
#define TT 512
#define II 512
#define HH 1024
#define OO 512
#define NBLK 256
#define NTHR 256
#define NB 16            // batches per group
#define US 16            // units per slice

// ws float-offsets
#define WS_HBUF  1280                      // 2 slots x 64x1024 fp16 = 65536 floats
#define WS_ASLAB 66816                     // 64s x 4mt x 48ks x 64ln uint4
#define WS_YSLAB 3212544                   // 64s x 32ks x 64ln uint4
#define BTO (BB*TT*OO)
#define BH  (BB*HH)

// LDS: x-acts [64 koct][16] uint4 (16KB) | h-acts [128 koct][16] uint4 (32KB)
//      | ypart [4][64][5] f32 (5KB, padded stride vs r13)
#define L_HB_U4 1024                       // uint4 index of h region
#define L_YP_F  12288                      // float index of ypart
#define L_BYTES ((12288 + 1280) * 4)       // 54272

typedef __fp16 v8hf __attribute__((ext_vector_type(8)));   // MFMA operand type
typedef float f32x4 __attribute__((ext_vector_type(4)));
typedef _Float16 h2 __attribute__((ext_vector_type(2)));

static __device__ __forceinline__ v8hf bc8(uint4 v) { return __builtin_bit_cast(v8hf, v); }
static __device__ __forceinline__ uint32_t pk_u32(float a, float b) {
  return __builtin_bit_cast(uint32_t, __builtin_amdgcn_cvt_pkrtz(a, b));
}

__device__ __forceinline__ float sigm(float v) { return 1.0f / (1.0f + __expf(-v)); }
__device__ __forceinline__ float tanh_c(float v) {
  v = fminf(fmaxf(v, -20.0f), 20.0f);
  float e = __expf(-2.0f * v);
  return (1.0f - e) / (1.0f + e);
}

// agent-scope (sc0 sc1): per-access coherence, NO cache-wide ops
__device__ __forceinline__ uint2 cohere_ld8(const void* p) {
  unsigned long long q = __hip_atomic_load((const unsigned long long*)p,
                                           __ATOMIC_RELAXED, __HIP_MEMORY_SCOPE_AGENT);
  return __builtin_bit_cast(uint2, q);
}
__device__ __forceinline__ void cohere_st8(void* p, uint32_t lo, uint32_t hi) {
  uint2 v = make_uint2(lo, hi);
  __hip_atomic_store((unsigned long long*)p, __builtin_bit_cast(unsigned long long, v),
                     __ATOMIC_RELAXED, __HIP_MEMORY_SCOPE_AGENT);
}

// -------- prep: pack A-slab (gate weights, MFMA A-frag order) + y-slab --------
__global__ void __launch_bounds__(256) prep(
    const float* __restrict__ Wf, const float* __restrict__ Wi,
    const float* __restrict__ Wc, const float* __restrict__ Wo,
    const float* __restrict__ Wfc, float* __restrict__ ws)
{
  const int NA = 64 * 4 * 48 * 64;
  const int NY = 64 * 32 * 64;
  int idx = blockIdx.x * 256 + threadIdx.x;
  if (idx < NA) {
    int s = idx / (4 * 48 * 64);
    int rem = idx % (4 * 48 * 64);
    int mt = rem / (48 * 64);
    int rem2 = rem % (48 * 64);
    int ks = rem2 >> 6, ln = rem2 & 63;
    int r = ln & 15, kq = ln >> 4;
    int unit = s * 16 + mt * 4 + (r >> 2), gate = r & 3;
    const float* W = (gate == 0) ? Wf : (gate == 1) ? Wi : (gate == 2) ? Wc : Wo;
    const float* src = W + (size_t)unit * 1536 + ks * 32 + kq * 8;
    uint32_t p[4];
    #pragma unroll
    for (int j = 0; j < 4; ++j) {
      h2 t; t.x = (_Float16)src[2*j]; t.y = (_Float16)src[2*j+1];   // RNE
      p[j] = __builtin_bit_cast(uint32_t, t);
    }
    ((uint4*)(ws + WS_ASLAB))[idx] = make_uint4(p[0], p[1], p[2], p[3]);
  } else if (idx < NA + NY) {
    int j2 = idx - NA;
    int s = j2 / (32 * 64);
    int rem = j2 % (32 * 64);
    int ks = rem >> 6, ln = rem & 63;
    int r = ln & 15, kq = ln >> 4;
    uint4 outv = make_uint4(0, 0, 0, 0);
    if (r < 8) {
      const float* src = Wfc + (size_t)(s * 8 + r) * 1024 + ks * 32 + kq * 8;
      uint32_t p[4];
      #pragma unroll
      for (int j = 0; j < 4; ++j) {
        h2 t; t.x = (_Float16)src[2*j]; t.y = (_Float16)src[2*j+1];
        p[j] = __builtin_bit_cast(uint32_t, t);
      }
      outv = make_uint4(p[0], p[1], p[2], p[3]);
    }
    ((uint4*)(ws + WS_YSLAB))[j2] = outv;
  }
}

__global__ void __launch_bounds__(NTHR, 1)
lstm_kernel(const float* __restrict__ x,
            const float* __restrict__ bf, const float* __restrict__ bi,
            const float* __restrict__ bc, const float* __restrict__ bo,
            const float* __restrict__ bfc,
            float* __restrict__ out, float* __restrict__ ws)
{
  extern __shared__ float ldsf[];
  uint4* acts4 = (uint4*)ldsf;               // x: [0,1024) ; h: [1024,3072)
  float* ypart = ldsf + L_YP_F;              // [4 waves][64 lanes][5]

  const int tid  = threadIdx.x;
  const int blk  = blockIdx.x;
  const int wave = tid >> 6;                 // == m-tile
  const int lane = tid & 63;
  const int g = blk >> 6, s = blk & 63;
  const int b0 = g * NB;
  const int u0 = s * US;

  uint32_t* ctrl  = (uint32_t*)ws;
  uint32_t* rootp = ctrl + g * 32;           // flat per-group counter (64 arrivals/step)
  ushort* hb16 = (ushort*)(ws + WS_HBUF);

  const int bq = lane & 15, kq = lane >> 4;  // B-col/batch ; k-group & C row-quad
  const int sb = tid >> 4, sj = tid & 15;    // staging: batch, 1/16 of row

  // ---- persistent A fragments: Aw (gate; ks 0..15 = x, 16..47 = h) + Yw ----
  v8hf Aw[48];
  v8hf Yw[8];
  {
    const uint4* wpA = (const uint4*)(ws + WS_ASLAB) + ((size_t)(s * 4 + wave) * 48) * 64 + lane;
    #pragma unroll
    for (int k = 0; k < 48; ++k) Aw[k] = bc8(wpA[k * 64]);
    const uint4* wpY = (const uint4*)(ws + WS_YSLAB) + ((size_t)(s * 32 + wave * 8)) * 64 + lane;
    #pragma unroll
    for (int k = 0; k < 8; ++k) Yw[k] = bc8(wpY[k * 64]);
  }
  const int unit = u0 + wave * 4 + kq;
  const float bsf = bf[unit], bsi = bi[unit], bsc = bc[unit], bso = bo[unit];
  const float ybias = (tid < 128) ? bfc[s * 8 + (tid >> 4)] : 0.0f;
  float cstate = 0.0f;
  f32x4 xacc[4];                             // x-part gate partials for step it

  // ---- prologue: stage x_0 ; zero h-LDS (h_{-1}=0) ; compute xacc(0) ----
  {
    const float* xs = x + ((size_t)(b0 + sb) * TT + 0) * II + sj * 32;
    #pragma unroll
    for (int v = 0; v < 4; ++v) {
      float4 u = ((const float4*)xs)[2*v], w = ((const float4*)xs)[2*v+1];
      acts4[sj * 64 + v * 16 + (sb ^ (sj & 7))] =
          make_uint4(pk_u32(u.x,u.y), pk_u32(u.z,u.w), pk_u32(w.x,w.y), pk_u32(w.z,w.w));
    }
    #pragma unroll
    for (int w = 0; w < 8; ++w) {
      int khb = sj * 2 + (w >> 2);
      acts4[L_HB_U4 + khb * 64 + (w & 3) * 16 + (sb ^ (khb & 7))] = make_uint4(0,0,0,0);
    }
  }
  __syncthreads();
  {
    #pragma unroll
    for (int j = 0; j < 4; ++j) xacc[j] = (f32x4){0.f, 0.f, 0.f, 0.f};
    #pragma unroll
    for (int ks = 0; ks < 16; ++ks) {
      uint4 bv = acts4[ks * 64 + kq * 16 + (bq ^ (ks & 7))];
      xacc[ks & 3] = __builtin_amdgcn_mfma_f32_16x16x32_f16(Aw[ks], bc8(bv), xacc[ks & 3], 0, 0, 0);
    }
  }

  for (int it = 0; it <= TT; ++it) {
    // ---- P0: x prefetch for it+1 (regs) ----
    float4 xr[8];
    const bool xok = (it + 1 < TT);
    if (xok) {
      const float* xs = x + ((size_t)(b0 + sb) * TT + (it + 1)) * II + sj * 32;
      #pragma unroll
      for (int v = 0; v < 8; ++v) xr[v] = ((const float4*)xs)[v];
    }

    if (it < TT) {
      // ---- P1: gate h-MFMA (32 k-steps over h_{it-1}) + xacc(it) ----
      f32x4 ac[4];
      #pragma unroll
      for (int j = 0; j < 4; ++j) ac[j] = xacc[j];
      #pragma unroll
      for (int ksh = 0; ksh < 32; ++ksh) {
        uint4 bv = acts4[L_HB_U4 + ksh * 64 + kq * 16 + (bq ^ (ksh & 7))];
        ac[ksh & 3] = __builtin_amdgcn_mfma_f32_16x16x32_f16(Aw[16 + ksh], bc8(bv), ac[ksh & 3], 0, 0, 0);
      }
      f32x4 t = (ac[0] + ac[1]) + (ac[2] + ac[3]);

      // ---- P2: state update + packed h store (ring slot (it+1)&1) ----
      float gf = sigm(t[0] + bsf);
      float gi = sigm(t[1] + bsi);
      float gc = tanh_c(t[2] + bsc);
      float go = sigm(t[3] + bso);
      cstate = gf * cstate + gi * gc;
      float hv = go * tanh_c(cstate);

      uint32_t hu = (uint32_t)__builtin_bit_cast(unsigned short, (_Float16)hv);
      uint32_t pA  = hu | ((uint32_t)__shfl_down((int)hu, 16) << 16);  // units q,q+1
      uint32_t hiw = (uint32_t)__shfl_down((int)pA, 32);               // units q+2,q+3
      if (kq == 0) {
        ushort* hp = hb16 + (size_t)((it + 1) & 1) * BH
                   + (size_t)(b0 + bq) * HH + (u0 + wave * 4);
        cohere_st8(hp, pA, hiw);
      }
      if (it == TT - 1) {
        out[(size_t)BTO + (size_t)(b0 + bq) * HH + unit] = hv;
        out[(size_t)BTO + BH + (size_t)(b0 + bq) * HH + unit] = cstate;
      }

      // ---- S_b + ARRIVE (flat counter, fire-and-forget: no return wait) ----
      asm volatile("s_waitcnt vmcnt(0)" ::: "memory");
      __syncthreads();
      if (tid == 0)
        (void)__hip_atomic_fetch_add(rootp, 1u, __ATOMIC_RELAXED, __HIP_MEMORY_SCOPE_AGENT);
    }

    // ======== barrier shadow: everything h_it-independent ========

    // ---- P3: y-MFMA for y_{it-1} (h_{it-1} still in h-LDS) ----
    if (it > 0) {
      f32x4 yc = (f32x4){0.f, 0.f, 0.f, 0.f};
      #pragma unroll
      for (int k = 0; k < 8; ++k) {
        int ksh = wave * 8 + k;
        uint4 bv = acts4[L_HB_U4 + ksh * 64 + kq * 16 + (bq ^ (ksh & 7))];
        yc = __builtin_amdgcn_mfma_f32_16x16x32_f16(Yw[k], bc8(bv), yc, 0, 0, 0);
      }
      float* yp = ypart + (wave * 64 + lane) * 5;
      yp[0] = yc[0]; yp[1] = yc[1]; yp[2] = yc[2]; yp[3] = yc[3];
    }

    // ---- P4: write x_{it+1} into x-LDS ----
    if (xok) {
      #pragma unroll
      for (int v = 0; v < 4; ++v)
        acts4[sj * 64 + v * 16 + (sb ^ (sj & 7))] =
            make_uint4(pk_u32(xr[2*v].x, xr[2*v].y), pk_u32(xr[2*v].z, xr[2*v].w),
                       pk_u32(xr[2*v+1].x, xr[2*v+1].y), pk_u32(xr[2*v+1].z, xr[2*v+1].w));
    }
    __syncthreads();                         // S_c: ypart + x-LDS ready

    // ---- y finalize: 128 threads, one (batch, out-col) each ----
    if (it > 0 && tid < 128) {
      int fb = tid & 15, rr = tid >> 4;      // rr = 0..7 -> o = s*8+rr
      int l = (rr >> 2) * 16 + fb;           // source lane (kq=rr>>2, bq=fb)
      float yv = ybias;
      #pragma unroll
      for (int w = 0; w < 4; ++w) yv += ypart[(w * 64 + l) * 5 + (rr & 3)];
      out[(size_t)(b0 + fb) * (TT * OO) + (size_t)(it - 1) * OO + s * 8 + rr] = yv;
    }

    // ---- P5: x-part gate MFMA for step it+1 ----
    if (xok) {
      #pragma unroll
      for (int j = 0; j < 4; ++j) xacc[j] = (f32x4){0.f, 0.f, 0.f, 0.f};
      #pragma unroll
      for (int ks = 0; ks < 16; ++ks) {
        uint4 bv = acts4[ks * 64 + kq * 16 + (bq ^ (ks & 7))];
        xacc[ks & 3] = __builtin_amdgcn_mfma_f32_16x16x32_f16(Aw[ks], bc8(bv), xacc[ks & 3], 0, 0, 0);
      }
    }

    if (it < TT) {
      // ---- WAIT: every thread polls (1 VMEM/wave/poll; no tid0 relay) ----
      {
        const uint32_t tgt = 64u * (uint32_t)(it + 1);
        while (__hip_atomic_load(rootp, __ATOMIC_RELAXED, __HIP_MEMORY_SCOPE_AGENT) < tgt)
          __builtin_amdgcn_s_sleep(1);
      }

      // ---- P6: gather h_it -> h-LDS ----
      {
        const ushort* hs = hb16 + (size_t)((it + 1) & 1) * BH
                         + (size_t)(b0 + sb) * HH + sj * 64;
        uint2 q[16];
        #pragma unroll
        for (int m = 0; m < 16; ++m) q[m] = cohere_ld8(hs + m * 4);
        #pragma unroll
        for (int w = 0; w < 8; ++w) {
          int khb = sj * 2 + (w >> 2);
          acts4[L_HB_U4 + khb * 64 + (w & 3) * 16 + (sb ^ (khb & 7))] =
              make_uint4(q[2*w].x, q[2*w].y, q[2*w+1].x, q[2*w+1].y);
        }
      }
      __syncthreads();                       // S_d: h ready for it+1
    }
  }
}

extern "C" void kernel_launch(void* const* d_in, const int* in_sizes, int n_in,
                              void* d_out, int out_size, void* d_ws, size_t ws_size,
                              hipStream_t stream) {
  (void)in_sizes; (void)n_in; (void)out_size; (void)ws_size;
  const float* x   = (const float*)d_in[0];
  const float* Wf  = (const float*)d_in[1];
  const float* bf  = (const float*)d_in[2];
  const float* Wi  = (const float*)d_in[3];
  const float* bi  = (const float*)d_in[4];
  const float* Wc  = (const float*)d_in[5];
  const float* bc  = (const float*)d_in[6];
  const float* Wo  = (const float*)d_in[7];
  const float* bo  = (const float*)d_in[8];
  const float* Wfc = (const float*)d_in[9];
  const float* bfc = (const float*)d_in[10];
  float* out = (float*)d_out;
  float* ws  = (float*)d_ws;

  // zero barrier counters; h slots are written before any read
  (void)hipMemsetAsync(d_ws, 0, (size_t)WS_HBUF * sizeof(float), stream);

  // pack fp16 MFMA fragment slabs
  const int nprep = 64 * 4 * 48 * 64 + 64 * 32 * 64;
  prep<<<dim3((nprep + 255) / 256), dim3(256), 0, stream>>>(Wf, Wi, Wc, Wo, Wfc, ws);

  // plain launch; 256 blocks <= 256 CUs => all co-resident for the spin barrier
  lstm_kernel<<<dim3(NBLK), dim3(NTHR), L_BYTES, stream>>>(
      x, bf, bi, bc, bo, bfc, out, ws);
}

// Round 15
// 3374.426 us; speedup vs baseline: 4.3783x; 1.1073x over previous
//
#include <hip/hip_runtime.h>
#include <stdint.h>

#define BB 64
#define TT 512
#define II 512
#define HH 1024
#define OO 512
#define NBLK 256
#define NTHR 512
#define NB 16            // batches per group
#define US 16            // units per slice

// ws float-offsets
#define WS_HBUF  1280                      // 2 slots x 64x1024 fp16 = 65536 floats
#define WS_ASLAB 66816                     // 64s x 4mt x 48ks x 64ln uint4
#define WS_YSLAB 3212544                   // 64s x 32ks x 64ln uint4
#define BTO (BB*TT*OO)
#define BH  (BB*HH)

// LDS: x-acts [64 koct][16] uint4 (16KB) | h-acts (32KB) | ypart [4][64][5] f32
//      | xpart [4][64][4] f32
#define L_HB_U4 1024                       // uint4 index of h region
#define L_YP_F  12288                      // float index of ypart
#define L_XP_F  (12288 + 1280)             // 13568
#define L_BYTES ((13568 + 1024) * 4)       // 58368

typedef __fp16 v8hf __attribute__((ext_vector_type(8)));   // MFMA operand type
typedef float f32x4 __attribute__((ext_vector_type(4)));
typedef _Float16 h2 __attribute__((ext_vector_type(2)));

static __device__ __forceinline__ v8hf bc8(uint4 v) { return __builtin_bit_cast(v8hf, v); }
static __device__ __forceinline__ uint32_t pk_u32(float a, float b) {
  return __builtin_bit_cast(uint32_t, __builtin_amdgcn_cvt_pkrtz(a, b));
}

__device__ __forceinline__ float sigm(float v) { return 1.0f / (1.0f + __expf(-v)); }
__device__ __forceinline__ float tanh_c(float v) {
  v = fminf(fmaxf(v, -20.0f), 20.0f);
  float e = __expf(-2.0f * v);
  return (1.0f - e) / (1.0f + e);
}

// agent-scope (sc0 sc1): per-access coherence, NO cache-wide ops
__device__ __forceinline__ uint2 cohere_ld8(const void* p) {
  unsigned long long q = __hip_atomic_load((const unsigned long long*)p,
                                           __ATOMIC_RELAXED, __HIP_MEMORY_SCOPE_AGENT);
  return __builtin_bit_cast(uint2, q);
}
__device__ __forceinline__ void cohere_st8(void* p, uint32_t lo, uint32_t hi) {
  uint2 v = make_uint2(lo, hi);
  __hip_atomic_store((unsigned long long*)p, __builtin_bit_cast(unsigned long long, v),
                     __ATOMIC_RELAXED, __HIP_MEMORY_SCOPE_AGENT);
}

// -------- prep: pack A-slab (gate weights, MFMA A-frag order) + y-slab --------
__global__ void __launch_bounds__(256) prep(
    const float* __restrict__ Wf, const float* __restrict__ Wi,
    const float* __restrict__ Wc, const float* __restrict__ Wo,
    const float* __restrict__ Wfc, float* __restrict__ ws)
{
  const int NA = 64 * 4 * 48 * 64;
  const int NY = 64 * 32 * 64;
  int idx = blockIdx.x * 256 + threadIdx.x;
  if (idx < NA) {
    int s = idx / (4 * 48 * 64);
    int rem = idx % (4 * 48 * 64);
    int mt = rem / (48 * 64);
    int rem2 = rem % (48 * 64);
    int ks = rem2 >> 6, ln = rem2 & 63;
    int r = ln & 15, kq = ln >> 4;
    int unit = s * 16 + mt * 4 + (r >> 2), gate = r & 3;
    const float* W = (gate == 0) ? Wf : (gate == 1) ? Wi : (gate == 2) ? Wc : Wo;
    const float* src = W + (size_t)unit * 1536 + ks * 32 + kq * 8;
    uint32_t p[4];
    #pragma unroll
    for (int j = 0; j < 4; ++j) {
      h2 t; t.x = (_Float16)src[2*j]; t.y = (_Float16)src[2*j+1];   // RNE
      p[j] = __builtin_bit_cast(uint32_t, t);
    }
    ((uint4*)(ws + WS_ASLAB))[idx] = make_uint4(p[0], p[1], p[2], p[3]);
  } else if (idx < NA + NY) {
    int j2 = idx - NA;
    int s = j2 / (32 * 64);
    int rem = j2 % (32 * 64);
    int ks = rem >> 6, ln = rem & 63;
    int r = ln & 15, kq = ln >> 4;
    uint4 outv = make_uint4(0, 0, 0, 0);
    if (r < 8) {
      const float* src = Wfc + (size_t)(s * 8 + r) * 1024 + ks * 32 + kq * 8;
      uint32_t p[4];
      #pragma unroll
      for (int j = 0; j < 4; ++j) {
        h2 t; t.x = (_Float16)src[2*j]; t.y = (_Float16)src[2*j+1];
        p[j] = __builtin_bit_cast(uint32_t, t);
      }
      outv = make_uint4(p[0], p[1], p[2], p[3]);
    }
    ((uint4*)(ws + WS_YSLAB))[j2] = outv;
  }
}

__global__ void __launch_bounds__(NTHR, 2)
lstm_kernel(const float* __restrict__ x,
            const float* __restrict__ bf, const float* __restrict__ bi,
            const float* __restrict__ bc, const float* __restrict__ bo,
            const float* __restrict__ bfc,
            float* __restrict__ out, float* __restrict__ ws)
{
  extern __shared__ float ldsf[];
  uint4* acts4 = (uint4*)ldsf;               // x: [0,1024) ; h: [1024,3072)
  float* ypart = ldsf + L_YP_F;              // [4][64][5]
  float* xpart = ldsf + L_XP_F;              // [4][64][4]

  const int tid  = threadIdx.x;
  const int blk  = blockIdx.x;
  const int wave = tid >> 6;
  const int lane = tid & 63;
  const bool isGate = (wave < 4);
  const int mt = wave & 3;                   // m-tile for this wave's role
  const int g = blk >> 6, s = blk & 63;
  const int b0 = g * NB;
  const int u0 = s * US;

  uint32_t* ctrl  = (uint32_t*)ws;
  uint32_t* rootp = ctrl + g * 32;           // flat per-group counter
  ushort* hb16 = (ushort*)(ws + WS_HBUF);

  const int bq = lane & 15, kq = lane >> 4;  // MFMA B-col/batch ; k-group & row-quad
  const int tid2 = tid & 255;                // aux staging index
  const int sb = tid2 >> 4, sj = tid2 & 15;  // x staging: batch, row/16
  const int gb = tid >> 5, gj = tid & 31;    // gather: batch, row/32 (512 thr)

  // ---- persistent fragments (role-split to fit 2 waves/SIMD) ----
  v8hf Ah[32];                               // gate: h-part A-frags (128 VGPR)
  v8hf Ax[16];                               // aux: x-part A-frags  (64 VGPR)
  v8hf Yw[8];                                // aux: Wfc k-slice     (32 VGPR)
  if (isGate) {
    const uint4* wpA = (const uint4*)(ws + WS_ASLAB)
                     + ((size_t)(s * 4 + mt) * 48 + 16) * 64 + lane;
    #pragma unroll
    for (int k = 0; k < 32; ++k) Ah[k] = bc8(wpA[k * 64]);
  } else {
    const uint4* wpA = (const uint4*)(ws + WS_ASLAB)
                     + ((size_t)(s * 4 + mt) * 48) * 64 + lane;
    #pragma unroll
    for (int k = 0; k < 16; ++k) Ax[k] = bc8(wpA[k * 64]);
    const uint4* wpY = (const uint4*)(ws + WS_YSLAB)
                     + ((size_t)(s * 32 + mt * 8)) * 64 + lane;
    #pragma unroll
    for (int k = 0; k < 8; ++k) Yw[k] = bc8(wpY[k * 64]);
  }
  const int unit = u0 + mt * 4 + kq;         // gate waves: owned unit
  const float bsf = isGate ? bf[unit] : 0.f;
  const float bsi = isGate ? bi[unit] : 0.f;
  const float bsc = isGate ? bc[unit] : 0.f;
  const float bso = isGate ? bo[unit] : 0.f;
  const float ybias = (tid < 128) ? bfc[s * 8 + (tid >> 4)] : 0.0f;
  float cstate = 0.0f;

  // ---- prologue ----
  if (!isGate) {                             // aux: stage x_0
    const float* xs = x + ((size_t)(b0 + sb) * TT + 0) * II + sj * 32;
    #pragma unroll
    for (int v = 0; v < 4; ++v) {
      float4 u = ((const float4*)xs)[2*v], w = ((const float4*)xs)[2*v+1];
      acts4[sj * 64 + v * 16 + (sb ^ (sj & 7))] =
          make_uint4(pk_u32(u.x,u.y), pk_u32(u.z,u.w), pk_u32(w.x,w.y), pk_u32(w.z,w.w));
    }
  } else {                                   // gate: zero h-LDS (h_{-1}=0)
    #pragma unroll
    for (int j = 0; j < 8; ++j)
      acts4[L_HB_U4 + tid2 * 8 + j] = make_uint4(0,0,0,0);
  }
  __syncthreads();
  if (!isGate) {                             // aux: xpart(0)
    f32x4 ac[4];
    #pragma unroll
    for (int j = 0; j < 4; ++j) ac[j] = (f32x4){0.f,0.f,0.f,0.f};
    #pragma unroll
    for (int ks = 0; ks < 16; ++ks) {
      uint4 bv = acts4[ks * 64 + kq * 16 + (bq ^ (ks & 7))];
      ac[ks & 3] = __builtin_amdgcn_mfma_f32_16x16x32_f16(Ax[ks], bc8(bv), ac[ks & 3], 0, 0, 0);
    }
    f32x4 t = (ac[0] + ac[1]) + (ac[2] + ac[3]);
    float* xp = xpart + (mt * 64 + lane) * 4;
    xp[0] = t[0]; xp[1] = t[1]; xp[2] = t[2]; xp[3] = t[3];
  }
  __syncthreads();

  for (int it = 0; it <= TT; ++it) {
    const bool xok = (it + 1 < TT);

    if (isGate) {
      // ---- GATE: C-init from xpart, 32 h-MFMA, state, h-store ----
      if (it < TT) {
        const float* xp = xpart + (mt * 64 + lane) * 4;
        f32x4 ac[4];
        ac[0] = (f32x4){xp[0], xp[1], xp[2], xp[3]};
        ac[1] = (f32x4){0.f,0.f,0.f,0.f};
        ac[2] = (f32x4){0.f,0.f,0.f,0.f};
        ac[3] = (f32x4){0.f,0.f,0.f,0.f};
        #pragma unroll
        for (int ksh = 0; ksh < 32; ++ksh) {
          uint4 bv = acts4[L_HB_U4 + ksh * 64 + kq * 16 + (bq ^ (ksh & 7))];
          ac[ksh & 3] = __builtin_amdgcn_mfma_f32_16x16x32_f16(Ah[ksh], bc8(bv), ac[ksh & 3], 0, 0, 0);
        }
        f32x4 t = (ac[0] + ac[1]) + (ac[2] + ac[3]);

        float gf = sigm(t[0] + bsf);
        float gi = sigm(t[1] + bsi);
        float gc = tanh_c(t[2] + bsc);
        float go = sigm(t[3] + bso);
        cstate = gf * cstate + gi * gc;
        float hv = go * tanh_c(cstate);

        uint32_t hu = (uint32_t)__builtin_bit_cast(unsigned short, (_Float16)hv);
        uint32_t pA  = hu | ((uint32_t)__shfl_down((int)hu, 16) << 16);
        uint32_t hiw = (uint32_t)__shfl_down((int)pA, 32);
        if (kq == 0) {
          ushort* hp = hb16 + (size_t)((it + 1) & 1) * BH
                     + (size_t)(b0 + bq) * HH + (u0 + mt * 4);
          cohere_st8(hp, pA, hiw);
        }
        if (it == TT - 1) {
          out[(size_t)BTO + (size_t)(b0 + bq) * HH + unit] = hv;
          out[(size_t)BTO + BH + (size_t)(b0 + bq) * HH + unit] = cstate;
        }
        asm volatile("s_waitcnt vmcnt(0)" ::: "memory");   // this wave's h drained
      }
    } else {
      // ---- AUX: y-MFMA for y_{it-1} over h_{it-1} (still in h-LDS) ----
      if (it > 0) {
        f32x4 yc = (f32x4){0.f,0.f,0.f,0.f};
        #pragma unroll
        for (int k = 0; k < 8; ++k) {
          int ksh = mt * 8 + k;
          uint4 bv = acts4[L_HB_U4 + ksh * 64 + kq * 16 + (bq ^ (ksh & 7))];
          yc = __builtin_amdgcn_mfma_f32_16x16x32_f16(Yw[k], bc8(bv), yc, 0, 0, 0);
        }
        float* yp = ypart + (mt * 64 + lane) * 5;
        yp[0] = yc[0]; yp[1] = yc[1]; yp[2] = yc[2]; yp[3] = yc[3];
      }
    }
    __syncthreads();                         // S1: h-LDS reads done; ypart ready

    // ---- ARRIVE (all gate waves' stores drained; fire-and-forget) ----
    if (it < TT && tid == 0)
      (void)__hip_atomic_fetch_add(rootp, 1u, __ATOMIC_RELAXED, __HIP_MEMORY_SCOPE_AGENT);

    // ---- gate threads: y finalize ; aux threads: x write ----
    if (tid < 128 && it > 0) {
      int fb = tid & 15, rr = tid >> 4;
      int l = (rr >> 2) * 16 + fb;
      float yv = ybias;
      #pragma unroll
      for (int w = 0; w < 4; ++w) yv += ypart[(w * 64 + l) * 5 + (rr & 3)];
      out[(size_t)(b0 + fb) * (TT * OO) + (size_t)(it - 1) * OO + s * 8 + rr] = yv;
    }
    if (!isGate && xok) {
      const float* xs = x + ((size_t)(b0 + sb) * TT + (it + 1)) * II + sj * 32;
      float4 xr[8];
      #pragma unroll
      for (int v = 0; v < 8; ++v) xr[v] = ((const float4*)xs)[v];
      #pragma unroll
      for (int v = 0; v < 4; ++v)
        acts4[sj * 64 + v * 16 + (sb ^ (sj & 7))] =
            make_uint4(pk_u32(xr[2*v].x, xr[2*v].y), pk_u32(xr[2*v].z, xr[2*v].w),
                       pk_u32(xr[2*v+1].x, xr[2*v+1].y), pk_u32(xr[2*v+1].z, xr[2*v+1].w));
    }
    __syncthreads();                         // S2: x-LDS ready

    // ---- aux: xpart(it+1) ----
    if (!isGate && xok) {
      f32x4 ac[4];
      #pragma unroll
      for (int j = 0; j < 4; ++j) ac[j] = (f32x4){0.f,0.f,0.f,0.f};
      #pragma unroll
      for (int ks = 0; ks < 16; ++ks) {
        uint4 bv = acts4[ks * 64 + kq * 16 + (bq ^ (ks & 7))];
        ac[ks & 3] = __builtin_amdgcn_mfma_f32_16x16x32_f16(Ax[ks], bc8(bv), ac[ks & 3], 0, 0, 0);
      }
      f32x4 t = (ac[0] + ac[1]) + (ac[2] + ac[3]);
      float* xp = xpart + (mt * 64 + lane) * 4;
      xp[0] = t[0]; xp[1] = t[1]; xp[2] = t[2]; xp[3] = t[3];
    }

    if (it < TT) {
      // ---- WAIT: all threads poll flat counter ----
      const uint32_t tgt = 64u * (uint32_t)(it + 1);
      while (__hip_atomic_load(rootp, __ATOMIC_RELAXED, __HIP_MEMORY_SCOPE_AGENT) < tgt)
        __builtin_amdgcn_s_sleep(1);

      // ---- gather h_it -> h-LDS (512 threads, 8B x 8 each) ----
      {
        const ushort* hs = hb16 + (size_t)((it + 1) & 1) * BH
                         + (size_t)(b0 + gb) * HH + gj * 32;
        uint2 q[8];
        #pragma unroll
        for (int m = 0; m < 8; ++m) q[m] = cohere_ld8(hs + m * 4);
        #pragma unroll
        for (int sub = 0; sub < 4; ++sub)
          acts4[L_HB_U4 + gj * 64 + sub * 16 + (gb ^ (gj & 7))] =
              make_uint4(q[2*sub].x, q[2*sub].y, q[2*sub+1].x, q[2*sub+1].y);
      }
      __syncthreads();                       // S3: h + xpart ready for it+1
    }
  }
}

extern "C" void kernel_launch(void* const* d_in, const int* in_sizes, int n_in,
                              void* d_out, int out_size, void* d_ws, size_t ws_size,
                              hipStream_t stream) {
  (void)in_sizes; (void)n_in; (void)out_size; (void)ws_size;
  const float* x   = (const float*)d_in[0];
  const float* Wf  = (const float*)d_in[1];
  const float* bf  = (const float*)d_in[2];
  const float* Wi  = (const float*)d_in[3];
  const float* bi  = (const float*)d_in[4];
  const float* Wc  = (const float*)d_in[5];
  const float* bc  = (const float*)d_in[6];
  const float* Wo  = (const float*)d_in[7];
  const float* bo  = (const float*)d_in[8];
  const float* Wfc = (const float*)d_in[9];
  const float* bfc = (const float*)d_in[10];
  float* out = (float*)d_out;
  float* ws  = (float*)d_ws;

  // zero barrier counters; h slots are written before any read
  (void)hipMemsetAsync(d_ws, 0, (size_t)WS_HBUF * sizeof(float), stream);

  // pack fp16 MFMA fragment slabs
  const int nprep = 64 * 4 * 48 * 64 + 64 * 32 * 64;
  prep<<<dim3((nprep + 255) / 256), dim3(256), 0, stream>>>(Wf, Wi, Wc, Wo, Wfc, ws);

  // plain launch; 256 blocks <= 256 CUs => all co-resident for the spin barrier
  lstm_kernel<<<dim3(NBLK), dim3(NTHR), L_BYTES, stream>>>(
      x, bf, bi, bc, bo, bfc, out, ws);
}

// Round 16
// 3330.283 us; speedup vs baseline: 4.4364x; 1.0133x over previous
//
#include <hip/hip_runtime.h>
#include <stdint.h>

#define BB 64
#define TT 512
#define II 512
#define HH 1024
#define OO 512
#define NBLK 256
#define NTHR 512
#define NB 16            // batches per group
#define US 16            // units per slice

// ws float-offsets
#define WS_HBUF  1280                      // 2 slots x 64x1024 fp16 = 65536 floats
#define WS_ASLAB 66816                     // 64s x 4mt x 48ks x 64ln uint4
#define WS_YSLAB 3212544                   // 64s x 32ks x 64ln uint4
#define BTO (BB*TT*OO)
#define BH  (BB*HH)

// LDS: x-acts [64 koct][16] uint4 (16KB) | h-acts (32KB) | ypart [4][64][5] f32
//      | xpart [4][64][4] f32
#define L_HB_U4 1024                       // uint4 index of h region
#define L_YP_F  12288                      // float index of ypart
#define L_XP_F  (12288 + 1280)             // 13568
#define L_BYTES ((13568 + 1024) * 4)       // 58368

typedef __fp16 v8hf __attribute__((ext_vector_type(8)));   // MFMA operand type
typedef float f32x4 __attribute__((ext_vector_type(4)));
typedef _Float16 h2 __attribute__((ext_vector_type(2)));

static __device__ __forceinline__ v8hf bc8(uint4 v) { return __builtin_bit_cast(v8hf, v); }
static __device__ __forceinline__ uint32_t pk_u32(float a, float b) {
  return __builtin_bit_cast(uint32_t, __builtin_amdgcn_cvt_pkrtz(a, b));
}

__device__ __forceinline__ float sigm(float v) { return 1.0f / (1.0f + __expf(-v)); }
__device__ __forceinline__ float tanh_c(float v) {
  v = fminf(fmaxf(v, -20.0f), 20.0f);
  float e = __expf(-2.0f * v);
  return (1.0f - e) / (1.0f + e);
}

// agent-scope (sc0 sc1): per-access coherence, NO cache-wide ops, NO atomics
__device__ __forceinline__ uint2 cohere_ld8(const void* p) {
  unsigned long long q = __hip_atomic_load((const unsigned long long*)p,
                                           __ATOMIC_RELAXED, __HIP_MEMORY_SCOPE_AGENT);
  return __builtin_bit_cast(uint2, q);
}
__device__ __forceinline__ void cohere_st8(void* p, uint32_t lo, uint32_t hi) {
  uint2 v = make_uint2(lo, hi);
  __hip_atomic_store((unsigned long long*)p, __builtin_bit_cast(unsigned long long, v),
                     __ATOMIC_RELAXED, __HIP_MEMORY_SCOPE_AGENT);
}
__device__ __forceinline__ void cohere_st4(void* p, uint32_t v) {
  __hip_atomic_store((uint32_t*)p, v, __ATOMIC_RELAXED, __HIP_MEMORY_SCOPE_AGENT);
}

// -------- prep: pack A-slab (gate weights, MFMA A-frag order) + y-slab --------
__global__ void __launch_bounds__(256) prep(
    const float* __restrict__ Wf, const float* __restrict__ Wi,
    const float* __restrict__ Wc, const float* __restrict__ Wo,
    const float* __restrict__ Wfc, float* __restrict__ ws)
{
  const int NA = 64 * 4 * 48 * 64;
  const int NY = 64 * 32 * 64;
  int idx = blockIdx.x * 256 + threadIdx.x;
  if (idx < NA) {
    int s = idx / (4 * 48 * 64);
    int rem = idx % (4 * 48 * 64);
    int mt = rem / (48 * 64);
    int rem2 = rem % (48 * 64);
    int ks = rem2 >> 6, ln = rem2 & 63;
    int r = ln & 15, kq = ln >> 4;
    int unit = s * 16 + mt * 4 + (r >> 2), gate = r & 3;
    const float* W = (gate == 0) ? Wf : (gate == 1) ? Wi : (gate == 2) ? Wc : Wo;
    const float* src = W + (size_t)unit * 1536 + ks * 32 + kq * 8;
    uint32_t p[4];
    #pragma unroll
    for (int j = 0; j < 4; ++j) {
      h2 t; t.x = (_Float16)src[2*j]; t.y = (_Float16)src[2*j+1];   // RNE
      p[j] = __builtin_bit_cast(uint32_t, t);
    }
    ((uint4*)(ws + WS_ASLAB))[idx] = make_uint4(p[0], p[1], p[2], p[3]);
  } else if (idx < NA + NY) {
    int j2 = idx - NA;
    int s = j2 / (32 * 64);
    int rem = j2 % (32 * 64);
    int ks = rem >> 6, ln = rem & 63;
    int r = ln & 15, kq = ln >> 4;
    uint4 outv = make_uint4(0, 0, 0, 0);
    if (r < 8) {
      const float* src = Wfc + (size_t)(s * 8 + r) * 1024 + ks * 32 + kq * 8;
      uint32_t p[4];
      #pragma unroll
      for (int j = 0; j < 4; ++j) {
        h2 t; t.x = (_Float16)src[2*j]; t.y = (_Float16)src[2*j+1];
        p[j] = __builtin_bit_cast(uint32_t, t);
      }
      outv = make_uint4(p[0], p[1], p[2], p[3]);
    }
    ((uint4*)(ws + WS_YSLAB))[j2] = outv;
  }
}

__global__ void __launch_bounds__(NTHR, 2)
lstm_kernel(const float* __restrict__ x,
            const float* __restrict__ bf, const float* __restrict__ bi,
            const float* __restrict__ bc, const float* __restrict__ bo,
            const float* __restrict__ bfc,
            float* __restrict__ out, float* __restrict__ ws)
{
  extern __shared__ float ldsf[];
  uint4* acts4 = (uint4*)ldsf;               // x: [0,1024) ; h: [1024,3072)
  float* ypart = ldsf + L_YP_F;              // [4][64][5]
  float* xpart = ldsf + L_XP_F;              // [4][64][4]

  const int tid  = threadIdx.x;
  const int blk  = blockIdx.x;
  const int wave = tid >> 6;
  const int lane = tid & 63;
  const bool isGate = (wave < 4);
  const int mt = wave & 3;                   // m-tile for this wave's role
  const int g = blk >> 6, s = blk & 63;
  const int b0 = g * NB;
  const int u0 = s * US;

  uint32_t* ctrl  = (uint32_t*)ws;
  uint32_t* flags = ctrl + g * 128;          // flags[s] = it+1, one word per block
  ushort* hb16 = (ushort*)(ws + WS_HBUF);

  const int bq = lane & 15, kq = lane >> 4;  // MFMA B-col/batch ; k-group & row-quad
  const int tid2 = tid & 255;                // aux staging index
  const int sb = tid2 >> 4, sj = tid2 & 15;  // x staging: batch, row/16
  const int gb = tid >> 5, gj = tid & 31;    // gather: batch, row/32 (512 thr)

  // ---- persistent fragments (role-split to fit 2 waves/SIMD) ----
  v8hf Ah[32];                               // gate: h-part A-frags (128 VGPR)
  v8hf Ax[16];                               // aux: x-part A-frags  (64 VGPR)
  v8hf Yw[8];                                // aux: Wfc k-slice     (32 VGPR)
  if (isGate) {
    const uint4* wpA = (const uint4*)(ws + WS_ASLAB)
                     + ((size_t)(s * 4 + mt) * 48 + 16) * 64 + lane;
    #pragma unroll
    for (int k = 0; k < 32; ++k) Ah[k] = bc8(wpA[k * 64]);
  } else {
    const uint4* wpA = (const uint4*)(ws + WS_ASLAB)
                     + ((size_t)(s * 4 + mt) * 48) * 64 + lane;
    #pragma unroll
    for (int k = 0; k < 16; ++k) Ax[k] = bc8(wpA[k * 64]);
    const uint4* wpY = (const uint4*)(ws + WS_YSLAB)
                     + ((size_t)(s * 32 + mt * 8)) * 64 + lane;
    #pragma unroll
    for (int k = 0; k < 8; ++k) Yw[k] = bc8(wpY[k * 64]);
  }
  const int unit = u0 + mt * 4 + kq;         // gate waves: owned unit
  const float bsf = isGate ? bf[unit] : 0.f;
  const float bsi = isGate ? bi[unit] : 0.f;
  const float bsc = isGate ? bc[unit] : 0.f;
  const float bso = isGate ? bo[unit] : 0.f;
  const float ybias = (tid < 128) ? bfc[s * 8 + (tid >> 4)] : 0.0f;
  float cstate = 0.0f;

  // ---- prologue ----
  if (!isGate) {                             // aux: stage x_0
    const float* xs = x + ((size_t)(b0 + sb) * TT + 0) * II + sj * 32;
    #pragma unroll
    for (int v = 0; v < 4; ++v) {
      float4 u = ((const float4*)xs)[2*v], w = ((const float4*)xs)[2*v+1];
      acts4[sj * 64 + v * 16 + (sb ^ (sj & 7))] =
          make_uint4(pk_u32(u.x,u.y), pk_u32(u.z,u.w), pk_u32(w.x,w.y), pk_u32(w.z,w.w));
    }
  } else {                                   // gate: zero h-LDS (h_{-1}=0)
    #pragma unroll
    for (int j = 0; j < 8; ++j)
      acts4[L_HB_U4 + tid2 * 8 + j] = make_uint4(0,0,0,0);
  }
  __syncthreads();
  if (!isGate) {                             // aux: xpart(0)
    f32x4 ac[4];
    #pragma unroll
    for (int j = 0; j < 4; ++j) ac[j] = (f32x4){0.f,0.f,0.f,0.f};
    #pragma unroll
    for (int ks = 0; ks < 16; ++ks) {
      uint4 bv = acts4[ks * 64 + kq * 16 + (bq ^ (ks & 7))];
      ac[ks & 3] = __builtin_amdgcn_mfma_f32_16x16x32_f16(Ax[ks], bc8(bv), ac[ks & 3], 0, 0, 0);
    }
    f32x4 t = (ac[0] + ac[1]) + (ac[2] + ac[3]);
    float* xp = xpart + (mt * 64 + lane) * 4;
    xp[0] = t[0]; xp[1] = t[1]; xp[2] = t[2]; xp[3] = t[3];
  }
  __syncthreads();

  for (int it = 0; it <= TT; ++it) {
    const bool xok = (it + 1 < TT);

    if (isGate) {
      // ---- GATE: C-init from xpart, 32 h-MFMA, state, h-store ----
      if (it < TT) {
        const float* xp = xpart + (mt * 64 + lane) * 4;
        f32x4 ac[4];
        ac[0] = (f32x4){xp[0], xp[1], xp[2], xp[3]};
        ac[1] = (f32x4){0.f,0.f,0.f,0.f};
        ac[2] = (f32x4){0.f,0.f,0.f,0.f};
        ac[3] = (f32x4){0.f,0.f,0.f,0.f};
        #pragma unroll
        for (int ksh = 0; ksh < 32; ++ksh) {
          uint4 bv = acts4[L_HB_U4 + ksh * 64 + kq * 16 + (bq ^ (ksh & 7))];
          ac[ksh & 3] = __builtin_amdgcn_mfma_f32_16x16x32_f16(Ah[ksh], bc8(bv), ac[ksh & 3], 0, 0, 0);
        }
        f32x4 t = (ac[0] + ac[1]) + (ac[2] + ac[3]);

        float gf = sigm(t[0] + bsf);
        float gi = sigm(t[1] + bsi);
        float gc = tanh_c(t[2] + bsc);
        float go = sigm(t[3] + bso);
        cstate = gf * cstate + gi * gc;
        float hv = go * tanh_c(cstate);

        uint32_t hu = (uint32_t)__builtin_bit_cast(unsigned short, (_Float16)hv);
        uint32_t pA  = hu | ((uint32_t)__shfl_down((int)hu, 16) << 16);
        uint32_t hiw = (uint32_t)__shfl_down((int)pA, 32);
        if (kq == 0) {
          ushort* hp = hb16 + (size_t)((it + 1) & 1) * BH
                     + (size_t)(b0 + bq) * HH + (u0 + mt * 4);
          cohere_st8(hp, pA, hiw);
        }
        if (it == TT - 1) {
          out[(size_t)BTO + (size_t)(b0 + bq) * HH + unit] = hv;
          out[(size_t)BTO + BH + (size_t)(b0 + bq) * HH + unit] = cstate;
        }
        asm volatile("s_waitcnt vmcnt(0)" ::: "memory");   // this wave's h drained
      }
    } else {
      // ---- AUX: y-MFMA for y_{it-1} over h_{it-1} (still in h-LDS) ----
      if (it > 0) {
        f32x4 yc = (f32x4){0.f,0.f,0.f,0.f};
        #pragma unroll
        for (int k = 0; k < 8; ++k) {
          int ksh = mt * 8 + k;
          uint4 bv = acts4[L_HB_U4 + ksh * 64 + kq * 16 + (bq ^ (ksh & 7))];
          yc = __builtin_amdgcn_mfma_f32_16x16x32_f16(Yw[k], bc8(bv), yc, 0, 0, 0);
        }
        float* yp = ypart + (mt * 64 + lane) * 5;
        yp[0] = yc[0]; yp[1] = yc[1]; yp[2] = yc[2]; yp[3] = yc[3];
      }
    }
    __syncthreads();                         // S1: h drained (gate waves), reads done

    // ---- PUBLISH: plain sc1 flag store, no atomic, no contention ----
    if (it < TT && tid == 0)
      cohere_st4(&flags[s], (uint32_t)(it + 1));

    // ---- gate threads: y finalize ; aux threads: x write ----
    if (tid < 128 && it > 0) {
      int fb = tid & 15, rr = tid >> 4;
      int l = (rr >> 2) * 16 + fb;
      float yv = ybias;
      #pragma unroll
      for (int w = 0; w < 4; ++w) yv += ypart[(w * 64 + l) * 5 + (rr & 3)];
      out[(size_t)(b0 + fb) * (TT * OO) + (size_t)(it - 1) * OO + s * 8 + rr] = yv;
    }
    if (!isGate && xok) {
      const float* xs = x + ((size_t)(b0 + sb) * TT + (it + 1)) * II + sj * 32;
      float4 xr[8];
      #pragma unroll
      for (int v = 0; v < 8; ++v) xr[v] = ((const float4*)xs)[v];
      #pragma unroll
      for (int v = 0; v < 4; ++v)
        acts4[sj * 64 + v * 16 + (sb ^ (sj & 7))] =
            make_uint4(pk_u32(xr[2*v].x, xr[2*v].y), pk_u32(xr[2*v].z, xr[2*v].w),
                       pk_u32(xr[2*v+1].x, xr[2*v+1].y), pk_u32(xr[2*v+1].z, xr[2*v+1].w));
    }
    __syncthreads();                         // S2: x-LDS ready

    // ---- aux: xpart(it+1) ----
    if (!isGate && xok) {
      f32x4 ac[4];
      #pragma unroll
      for (int j = 0; j < 4; ++j) ac[j] = (f32x4){0.f,0.f,0.f,0.f};
      #pragma unroll
      for (int ks = 0; ks < 16; ++ks) {
        uint4 bv = acts4[ks * 64 + kq * 16 + (bq ^ (ks & 7))];
        ac[ks & 3] = __builtin_amdgcn_mfma_f32_16x16x32_f16(Ax[ks], bc8(bv), ac[ks & 3], 0, 0, 0);
      }
      f32x4 t = (ac[0] + ac[1]) + (ac[2] + ac[3]);
      float* xp = xpart + (mt * 64 + lane) * 4;
      xp[0] = t[0]; xp[1] = t[1]; xp[2] = t[2]; xp[3] = t[3];
    }

    if (it < TT) {
      // ---- DATAFLOW WAIT+GATHER: each thread waits only for ITS 2 producers ----
      {
        const uint32_t tgt = (uint32_t)(it + 1);
        for (;;) {
          uint2 f = cohere_ld8(&flags[gj * 2]);
          if (f.x >= tgt && f.y >= tgt) break;
          __builtin_amdgcn_s_sleep(1);
        }
        const ushort* hs = hb16 + (size_t)((it + 1) & 1) * BH
                         + (size_t)(b0 + gb) * HH + gj * 32;
        uint2 q[8];
        #pragma unroll
        for (int m = 0; m < 8; ++m) q[m] = cohere_ld8(hs + m * 4);
        #pragma unroll
        for (int sub = 0; sub < 4; ++sub)
          acts4[L_HB_U4 + gj * 64 + sub * 16 + (gb ^ (gj & 7))] =
              make_uint4(q[2*sub].x, q[2*sub].y, q[2*sub+1].x, q[2*sub+1].y);
      }
      __syncthreads();                       // S3: h + xpart ready for it+1
    }
  }
}

extern "C" void kernel_launch(void* const* d_in, const int* in_sizes, int n_in,
                              void* d_out, int out_size, void* d_ws, size_t ws_size,
                              hipStream_t stream) {
  (void)in_sizes; (void)n_in; (void)out_size; (void)ws_size;
  const float* x   = (const float*)d_in[0];
  const float* Wf  = (const float*)d_in[1];
  const float* bf  = (const float*)d_in[2];
  const float* Wi  = (const float*)d_in[3];
  const float* bi  = (const float*)d_in[4];
  const float* Wc  = (const float*)d_in[5];
  const float* bc  = (const float*)d_in[6];
  const float* Wo  = (const float*)d_in[7];
  const float* bo  = (const float*)d_in[8];
  const float* Wfc = (const float*)d_in[9];
  const float* bfc = (const float*)d_in[10];
  float* out = (float*)d_out;
  float* ws  = (float*)d_ws;

  // zero flag words; h slots are written before any read
  (void)hipMemsetAsync(d_ws, 0, (size_t)WS_HBUF * sizeof(float), stream);

  // pack fp16 MFMA fragment slabs
  const int nprep = 64 * 4 * 48 * 64 + 64 * 32 * 64;
  prep<<<dim3((nprep + 255) / 256), dim3(256), 0, stream>>>(Wf, Wi, Wc, Wo, Wfc, ws);

  // plain launch; 256 blocks <= 256 CUs => all co-resident for the spin barrier
  lstm_kernel<<<dim3(NBLK), dim3(NTHR), L_BYTES, stream>>>(
      x, bf, bi, bc, bo, bfc, out, ws);
}